// Round 2
// baseline (8618.802 us; speedup 1.0000x reference)
//
#include <hip/hip_runtime.h>

static constexpr int       NN = 1000000;
static constexpr long long NE = 16000000;
static constexpr int       F  = 6;

// ---------------------------------------------------------------------------
// Scatter layer 1: agg[dst] += (double)x[src]   (6 fp64 hw atomics / edge)
// edge_index arrives as int32 (harness converts all ints to int32).
// ---------------------------------------------------------------------------
__global__ __launch_bounds__(256) void k_scatter_x(
    const float* __restrict__ x, const int* __restrict__ ei,
    double* __restrict__ agg)
{
    long long e = (long long)blockIdx.x * blockDim.x + threadIdx.x;
    if (e >= NE) return;
    int s = ei[e];
    int d = ei[NE + e];
    const float* xr = x + (long long)s * F;
    double* ar = agg + (long long)d * F;
    float2 a = *(const float2*)(xr + 0);
    float2 b = *(const float2*)(xr + 2);
    float2 c = *(const float2*)(xr + 4);
    unsafeAtomicAdd(ar + 0, (double)a.x);
    unsafeAtomicAdd(ar + 1, (double)a.y);
    unsafeAtomicAdd(ar + 2, (double)b.x);
    unsafeAtomicAdd(ar + 3, (double)b.y);
    unsafeAtomicAdd(ar + 4, (double)c.x);
    unsafeAtomicAdd(ar + 5, (double)c.y);
}

// ---------------------------------------------------------------------------
// Scatter layer 2 (fp64 h1): agg[dst] += h1[src]
// ---------------------------------------------------------------------------
__global__ __launch_bounds__(256) void k_scatter_h64(
    const double* __restrict__ h, const int* __restrict__ ei,
    double* __restrict__ agg)
{
    long long e = (long long)blockIdx.x * blockDim.x + threadIdx.x;
    if (e >= NE) return;
    int s = ei[e];
    int d = ei[NE + e];
    const double* hr = h + (long long)s * F;
    double* ar = agg + (long long)d * F;
    #pragma unroll
    for (int k = 0; k < F; ++k) unsafeAtomicAdd(ar + k, hr[k]);
}

// ---------------------------------------------------------------------------
// Scatter layer 2 (fp32 h1 fallback): agg[dst] += (double)h1f[src]
// ---------------------------------------------------------------------------
__global__ __launch_bounds__(256) void k_scatter_h32(
    const float* __restrict__ h, const int* __restrict__ ei,
    double* __restrict__ agg)
{
    long long e = (long long)blockIdx.x * blockDim.x + threadIdx.x;
    if (e >= NE) return;
    int s = ei[e];
    int d = ei[NE + e];
    const float* hr = h + (long long)s * F;
    double* ar = agg + (long long)d * F;
    float2 a = *(const float2*)(hr + 0);
    float2 b = *(const float2*)(hr + 2);
    float2 c = *(const float2*)(hr + 4);
    unsafeAtomicAdd(ar + 0, (double)a.x);
    unsafeAtomicAdd(ar + 1, (double)a.y);
    unsafeAtomicAdd(ar + 2, (double)b.x);
    unsafeAtomicAdd(ar + 3, (double)b.y);
    unsafeAtomicAdd(ar + 4, (double)c.x);
    unsafeAtomicAdd(ar + 5, (double)c.y);
}

// ---------------------------------------------------------------------------
// Layer-1 node linear: h1 = agg @ Wrel1.T + b1 + x @ Wroot1.T   (fp64 math)
// Templated on output type (double primary / float fallback).
// ---------------------------------------------------------------------------
template <typename OutT>
__global__ __launch_bounds__(256) void k_lin1(
    const float* __restrict__ x, const double* __restrict__ agg,
    const float* __restrict__ Wrel, const float* __restrict__ Wroot,
    const float* __restrict__ bias, OutT* __restrict__ h)
{
    __shared__ double sR[F * F], sT[F * F], sB[F];
    int t = threadIdx.x;
    if (t < F * F) { sR[t] = (double)Wrel[t]; sT[t] = (double)Wroot[t]; }
    if (t < F) sB[t] = (double)bias[t];
    __syncthreads();
    long long i = (long long)blockIdx.x * blockDim.x + t;
    if (i >= NN) return;
    const float*  xr = x   + i * F;
    const double* ar = agg + i * F;
    double xv[F], av[F];
    #pragma unroll
    for (int j = 0; j < F; ++j) { xv[j] = (double)xr[j]; av[j] = ar[j]; }
    OutT* hr = h + i * F;
    #pragma unroll
    for (int k = 0; k < F; ++k) {
        double acc = sB[k];
        #pragma unroll
        for (int j = 0; j < F; ++j)
            acc += av[j] * sR[k * F + j] + xv[j] * sT[k * F + j];
        hr[k] = (OutT)acc;
    }
}

// ---------------------------------------------------------------------------
// Layer-2 node linear + argmax + one-hot (h2 never materialized)
// ---------------------------------------------------------------------------
template <typename H1T>
__global__ __launch_bounds__(256) void k_lin2_argmax(
    const H1T* __restrict__ h1, const double* __restrict__ agg,
    const float* __restrict__ Wrel, const float* __restrict__ Wroot,
    const float* __restrict__ bias, float* __restrict__ out)
{
    __shared__ double sR[F * F], sT[F * F], sB[F];
    int t = threadIdx.x;
    if (t < F * F) { sR[t] = (double)Wrel[t]; sT[t] = (double)Wroot[t]; }
    if (t < F) sB[t] = (double)bias[t];
    __syncthreads();
    long long i = (long long)blockIdx.x * blockDim.x + t;
    if (i >= NN) return;
    const H1T*    hr = h1  + i * F;
    const double* ar = agg + i * F;
    double hv[F], av[F];
    #pragma unroll
    for (int j = 0; j < F; ++j) { hv[j] = (double)hr[j]; av[j] = ar[j]; }
    double h2[F];
    #pragma unroll
    for (int k = 0; k < F; ++k) {
        double acc = sB[k];
        #pragma unroll
        for (int j = 0; j < F; ++j)
            acc += av[j] * sR[k * F + j] + hv[j] * sT[k * F + j];
        h2[k] = acc;
    }
    // first-occurrence argmax (jnp.argmax semantics): strict > keeps first
    int best = 0;
    double bv = h2[0];
    #pragma unroll
    for (int k = 1; k < F; ++k)
        if (h2[k] > bv) { bv = h2[k]; best = k; }
    float* o = out + i * F;
    #pragma unroll
    for (int k = 0; k < F; ++k) o[k] = (k == best) ? 1.0f : 0.0f;
}

extern "C" void kernel_launch(void* const* d_in, const int* in_sizes, int n_in,
                              void* d_out, int out_size, void* d_ws, size_t ws_size,
                              hipStream_t stream) {
    const float* x      = (const float*)d_in[0];
    const int*   ei     = (const int*)d_in[1];     // int32 per harness contract
    const float* Wrel1  = (const float*)d_in[2];
    const float* Wroot1 = (const float*)d_in[3];
    const float* b1     = (const float*)d_in[4];
    const float* Wrel2  = (const float*)d_in[5];
    const float* Wroot2 = (const float*)d_in[6];
    const float* b2     = (const float*)d_in[7];
    float* out = (float*)d_out;

    double* agg = (double*)d_ws;                  // 6M doubles = 48 MB
    const size_t aggBytes = (size_t)NN * F * sizeof(double);
    const int eb = (int)((NE + 255) / 256);
    const int nb = (NN + 255) / 256;

    if (ws_size >= 2 * aggBytes) {
        // Primary: fp64 h1 in ws
        double* h1 = agg + (size_t)NN * F;        // +48 MB
        hipMemsetAsync(agg, 0, aggBytes, stream);
        k_scatter_x<<<eb, 256, 0, stream>>>(x, ei, agg);
        k_lin1<double><<<nb, 256, 0, stream>>>(x, agg, Wrel1, Wroot1, b1, h1);
        hipMemsetAsync(agg, 0, aggBytes, stream);
        k_scatter_h64<<<eb, 256, 0, stream>>>(h1, ei, agg);
        k_lin2_argmax<double><<<nb, 256, 0, stream>>>(h1, agg, Wrel2, Wroot2, b2, out);
    } else {
        // Fallback: fp32 h1 staged in d_out (overwritten by one-hot at the end)
        float* h1f = out;
        hipMemsetAsync(agg, 0, aggBytes, stream);
        k_scatter_x<<<eb, 256, 0, stream>>>(x, ei, agg);
        k_lin1<float><<<nb, 256, 0, stream>>>(x, agg, Wrel1, Wroot1, b1, h1f);
        hipMemsetAsync(agg, 0, aggBytes, stream);
        k_scatter_h32<<<eb, 256, 0, stream>>>(h1f, ei, agg);
        k_lin2_argmax<float><<<nb, 256, 0, stream>>>(h1f, agg, Wrel2, Wroot2, b2, out);
    }
}

// Round 3
// 2907.733 us; speedup vs baseline: 2.9641x; 2.9641x over previous
//
#include <hip/hip_runtime.h>

static constexpr int       NN = 1000000;
static constexpr long long NE = 16000000;
static constexpr int       F  = 6;
static constexpr int       SCAN_B = 256;
static constexpr int       NB_SCAN = (NN + SCAN_B - 1) / SCAN_B;   // 3907

// ============================ CSR build =====================================
// K1: histogram of dst into cursor[]
__global__ __launch_bounds__(256) void k_hist(
    const int* __restrict__ ei, int* __restrict__ cnt)
{
    long long e = (long long)blockIdx.x * blockDim.x + threadIdx.x;
    if (e >= NE) return;
    atomicAdd(&cnt[ei[NE + e]], 1);
}

// K2a: per-block sums of cnt
__global__ __launch_bounds__(SCAN_B) void k_scan_bsum(
    const int* __restrict__ cnt, int* __restrict__ bsum)
{
    __shared__ int s[SCAN_B];
    int i = blockIdx.x * SCAN_B + threadIdx.x;
    int v = (i < NN) ? cnt[i] : 0;
    s[threadIdx.x] = v;
    __syncthreads();
    for (int off = SCAN_B / 2; off > 0; off >>= 1) {
        if (threadIdx.x < off) s[threadIdx.x] += s[threadIdx.x + off];
        __syncthreads();
    }
    if (threadIdx.x == 0) bsum[blockIdx.x] = s[0];
}

// K2b: exclusive scan of bsum (single block)
__global__ __launch_bounds__(SCAN_B) void k_scan_top(int* __restrict__ bsum, int n)
{
    __shared__ int s[SCAN_B];
    __shared__ int carry;
    if (threadIdx.x == 0) carry = 0;
    __syncthreads();
    for (int base = 0; base < n; base += SCAN_B) {
        int i = base + threadIdx.x;
        int v = (i < n) ? bsum[i] : 0;
        s[threadIdx.x] = v;
        __syncthreads();
        // Hillis-Steele inclusive scan
        for (int off = 1; off < SCAN_B; off <<= 1) {
            int t = (threadIdx.x >= off) ? s[threadIdx.x - off] : 0;
            __syncthreads();
            s[threadIdx.x] += t;
            __syncthreads();
        }
        int incl = s[threadIdx.x];
        int total = s[SCAN_B - 1];
        if (i < n) bsum[i] = incl - v + carry;   // exclusive + carry
        __syncthreads();
        if (threadIdx.x == 0) carry += total;
        __syncthreads();
    }
}

// K2c: per-block exclusive scan + bsum offset, in place (cnt -> offsets)
__global__ __launch_bounds__(SCAN_B) void k_scan_final(
    int* __restrict__ cnt, const int* __restrict__ bsum)
{
    __shared__ int s[SCAN_B];
    int i = blockIdx.x * SCAN_B + threadIdx.x;
    int v = (i < NN) ? cnt[i] : 0;
    s[threadIdx.x] = v;
    __syncthreads();
    for (int off = 1; off < SCAN_B; off <<= 1) {
        int t = (threadIdx.x >= off) ? s[threadIdx.x - off] : 0;
        __syncthreads();
        s[threadIdx.x] += t;
        __syncthreads();
    }
    if (i < NN) cnt[i] = s[threadIdx.x] - v + bsum[blockIdx.x];
}

// K3: scatter edge srcs into CSR slots; cursor advances to end-offsets
__global__ __launch_bounds__(256) void k_fill(
    const int* __restrict__ ei, int* __restrict__ cursor,
    int* __restrict__ srt)
{
    long long e = (long long)blockIdx.x * blockDim.x + threadIdx.x;
    if (e >= NE) return;
    int s = ei[e];
    int d = ei[NE + e];
    int pos = atomicAdd(&cursor[d], 1);
    srt[pos] = s;
}

// ======================== fused GNN passes ==================================
// K4: layer-1 gather + linear; h1 stored as exact float hi/lo pair
__global__ __launch_bounds__(256) void k_layer1(
    const float* __restrict__ x, const int* __restrict__ ends,
    const int* __restrict__ srt,
    const float* __restrict__ Wrel, const float* __restrict__ Wroot,
    const float* __restrict__ bias,
    float* __restrict__ h_hi, float* __restrict__ h_lo)
{
    __shared__ double sR[F * F], sT[F * F], sB[F];
    int t = threadIdx.x;
    if (t < F * F) { sR[t] = (double)Wrel[t]; sT[t] = (double)Wroot[t]; }
    if (t < F) sB[t] = (double)bias[t];
    __syncthreads();
    int i = blockIdx.x * blockDim.x + t;
    if (i >= NN) return;
    int p0 = (i == 0) ? 0 : ends[i - 1];
    int p1 = ends[i];
    double acc[F] = {0, 0, 0, 0, 0, 0};
    for (int p = p0; p < p1; ++p) {
        const float* xr = x + (long long)srt[p] * F;
        float2 a = *(const float2*)(xr + 0);
        float2 b = *(const float2*)(xr + 2);
        float2 c = *(const float2*)(xr + 4);
        acc[0] += (double)a.x; acc[1] += (double)a.y;
        acc[2] += (double)b.x; acc[3] += (double)b.y;
        acc[4] += (double)c.x; acc[5] += (double)c.y;
    }
    const float* xi = x + (long long)i * F;
    double xv[F];
    #pragma unroll
    for (int j = 0; j < F; ++j) xv[j] = (double)xi[j];
    float* hh = h_hi + (long long)i * F;
    float* hl = h_lo + (long long)i * F;
    #pragma unroll
    for (int k = 0; k < F; ++k) {
        double h = sB[k];
        #pragma unroll
        for (int j = 0; j < F; ++j)
            h += acc[j] * sR[k * F + j] + xv[j] * sT[k * F + j];
        float hi = (float)h;
        hh[k] = hi;
        hl[k] = (float)(h - (double)hi);
    }
}

// K5: layer-2 gather + linear + argmax -> best index (1 byte/node)
__global__ __launch_bounds__(256) void k_layer2(
    const float* __restrict__ h_hi, const float* __restrict__ h_lo,
    const int* __restrict__ ends, const int* __restrict__ srt,
    const float* __restrict__ Wrel, const float* __restrict__ Wroot,
    const float* __restrict__ bias, unsigned char* __restrict__ best)
{
    __shared__ double sR[F * F], sT[F * F], sB[F];
    int t = threadIdx.x;
    if (t < F * F) { sR[t] = (double)Wrel[t]; sT[t] = (double)Wroot[t]; }
    if (t < F) sB[t] = (double)bias[t];
    __syncthreads();
    int i = blockIdx.x * blockDim.x + t;
    if (i >= NN) return;
    int p0 = (i == 0) ? 0 : ends[i - 1];
    int p1 = ends[i];
    double acc[F] = {0, 0, 0, 0, 0, 0};
    for (int p = p0; p < p1; ++p) {
        long long r = (long long)srt[p] * F;
        float2 a = *(const float2*)(h_hi + r + 0);
        float2 b = *(const float2*)(h_hi + r + 2);
        float2 c = *(const float2*)(h_hi + r + 4);
        float2 la = *(const float2*)(h_lo + r + 0);
        float2 lb = *(const float2*)(h_lo + r + 2);
        float2 lc = *(const float2*)(h_lo + r + 4);
        acc[0] += (double)a.x + (double)la.x;
        acc[1] += (double)a.y + (double)la.y;
        acc[2] += (double)b.x + (double)lb.x;
        acc[3] += (double)b.y + (double)lb.y;
        acc[4] += (double)c.x + (double)lc.x;
        acc[5] += (double)c.y + (double)lc.y;
    }
    long long ri = (long long)i * F;
    double hv[F];
    #pragma unroll
    for (int j = 0; j < F; ++j)
        hv[j] = (double)h_hi[ri + j] + (double)h_lo[ri + j];
    double h2[F];
    #pragma unroll
    for (int k = 0; k < F; ++k) {
        double h = sB[k];
        #pragma unroll
        for (int j = 0; j < F; ++j)
            h += acc[j] * sR[k * F + j] + hv[j] * sT[k * F + j];
        h2[k] = h;
    }
    int b = 0;
    double bv = h2[0];
    #pragma unroll
    for (int k = 1; k < F; ++k)
        if (h2[k] > bv) { bv = h2[k]; b = k; }
    best[i] = (unsigned char)b;
}

// K6: expand one-hot
__global__ __launch_bounds__(256) void k_onehot(
    const unsigned char* __restrict__ best, float* __restrict__ out)
{
    int i = blockIdx.x * blockDim.x + threadIdx.x;
    if (i >= NN) return;
    int b = best[i];
    float* o = out + (long long)i * F;
    #pragma unroll
    for (int k = 0; k < F; ++k) o[k] = (k == b) ? 1.0f : 0.0f;
}

// ===================== round-2 fallback (atomic path) =======================
__global__ __launch_bounds__(256) void k_scatter_x(
    const float* __restrict__ x, const int* __restrict__ ei,
    double* __restrict__ agg)
{
    long long e = (long long)blockIdx.x * blockDim.x + threadIdx.x;
    if (e >= NE) return;
    int s = ei[e];
    int d = ei[NE + e];
    const float* xr = x + (long long)s * F;
    double* ar = agg + (long long)d * F;
    float2 a = *(const float2*)(xr + 0);
    float2 b = *(const float2*)(xr + 2);
    float2 c = *(const float2*)(xr + 4);
    unsafeAtomicAdd(ar + 0, (double)a.x);
    unsafeAtomicAdd(ar + 1, (double)a.y);
    unsafeAtomicAdd(ar + 2, (double)b.x);
    unsafeAtomicAdd(ar + 3, (double)b.y);
    unsafeAtomicAdd(ar + 4, (double)c.x);
    unsafeAtomicAdd(ar + 5, (double)c.y);
}

__global__ __launch_bounds__(256) void k_scatter_h32(
    const float* __restrict__ h, const int* __restrict__ ei,
    double* __restrict__ agg)
{
    long long e = (long long)blockIdx.x * blockDim.x + threadIdx.x;
    if (e >= NE) return;
    int s = ei[e];
    int d = ei[NE + e];
    const float* hr = h + (long long)s * F;
    double* ar = agg + (long long)d * F;
    float2 a = *(const float2*)(hr + 0);
    float2 b = *(const float2*)(hr + 2);
    float2 c = *(const float2*)(hr + 4);
    unsafeAtomicAdd(ar + 0, (double)a.x);
    unsafeAtomicAdd(ar + 1, (double)a.y);
    unsafeAtomicAdd(ar + 2, (double)b.x);
    unsafeAtomicAdd(ar + 3, (double)b.y);
    unsafeAtomicAdd(ar + 4, (double)c.x);
    unsafeAtomicAdd(ar + 5, (double)c.y);
}

__global__ __launch_bounds__(256) void k_lin1_f(
    const float* __restrict__ x, const double* __restrict__ agg,
    const float* __restrict__ Wrel, const float* __restrict__ Wroot,
    const float* __restrict__ bias, float* __restrict__ h)
{
    __shared__ double sR[F * F], sT[F * F], sB[F];
    int t = threadIdx.x;
    if (t < F * F) { sR[t] = (double)Wrel[t]; sT[t] = (double)Wroot[t]; }
    if (t < F) sB[t] = (double)bias[t];
    __syncthreads();
    long long i = (long long)blockIdx.x * blockDim.x + t;
    if (i >= NN) return;
    const float*  xr = x + i * F;
    const double* ar = agg + i * F;
    double xv[F], av[F];
    #pragma unroll
    for (int j = 0; j < F; ++j) { xv[j] = (double)xr[j]; av[j] = ar[j]; }
    float* hr = h + i * F;
    #pragma unroll
    for (int k = 0; k < F; ++k) {
        double a = sB[k];
        #pragma unroll
        for (int j = 0; j < F; ++j)
            a += av[j] * sR[k * F + j] + xv[j] * sT[k * F + j];
        hr[k] = (float)a;
    }
}

__global__ __launch_bounds__(256) void k_lin2_f(
    const float* __restrict__ h1, const double* __restrict__ agg,
    const float* __restrict__ Wrel, const float* __restrict__ Wroot,
    const float* __restrict__ bias, float* __restrict__ out)
{
    __shared__ double sR[F * F], sT[F * F], sB[F];
    int t = threadIdx.x;
    if (t < F * F) { sR[t] = (double)Wrel[t]; sT[t] = (double)Wroot[t]; }
    if (t < F) sB[t] = (double)bias[t];
    __syncthreads();
    long long i = (long long)blockIdx.x * blockDim.x + t;
    if (i >= NN) return;
    const float*  hr = h1 + i * F;
    const double* ar = agg + i * F;
    double hv[F], av[F];
    #pragma unroll
    for (int j = 0; j < F; ++j) { hv[j] = (double)hr[j]; av[j] = ar[j]; }
    double h2[F];
    #pragma unroll
    for (int k = 0; k < F; ++k) {
        double a = sB[k];
        #pragma unroll
        for (int j = 0; j < F; ++j)
            a += av[j] * sR[k * F + j] + hv[j] * sT[k * F + j];
        h2[k] = a;
    }
    int b = 0;
    double bv = h2[0];
    #pragma unroll
    for (int k = 1; k < F; ++k)
        if (h2[k] > bv) { bv = h2[k]; b = k; }
    float* o = out + i * F;
    #pragma unroll
    for (int k = 0; k < F; ++k) o[k] = (k == b) ? 1.0f : 0.0f;
}

// ============================================================================
extern "C" void kernel_launch(void* const* d_in, const int* in_sizes, int n_in,
                              void* d_out, int out_size, void* d_ws, size_t ws_size,
                              hipStream_t stream) {
    const float* x      = (const float*)d_in[0];
    const int*   ei     = (const int*)d_in[1];     // int32 per harness contract
    const float* Wrel1  = (const float*)d_in[2];
    const float* Wroot1 = (const float*)d_in[3];
    const float* b1     = (const float*)d_in[4];
    const float* Wrel2  = (const float*)d_in[5];
    const float* Wroot2 = (const float*)d_in[6];
    const float* b2     = (const float*)d_in[7];
    float* out = (float*)d_out;

    const int eb = (int)((NE + 255) / 256);
    const int nb = (NN + 255) / 256;

    // ws layout (CSR path)
    size_t o_srt  = 0;                                   // int[16M]  = 64 MB
    size_t o_cur  = o_srt + (size_t)NE * 4;              // int[NN]   =  4 MB
    size_t o_bsum = o_cur + (size_t)NN * 4;              // int[3907] ~ 16 KB
    size_t o_hlo  = o_bsum + 16384;                      // float[6M] = 24 MB
    size_t o_best = o_hlo + (size_t)NN * F * 4;          // u8[NN]    =  1 MB
    size_t need   = o_best + (size_t)NN;

    if (ws_size >= need) {
        char* ws = (char*)d_ws;
        int*  srt    = (int*)(ws + o_srt);
        int*  cursor = (int*)(ws + o_cur);
        int*  bsum   = (int*)(ws + o_bsum);
        float* h_lo  = (float*)(ws + o_hlo);
        unsigned char* best = (unsigned char*)(ws + o_best);
        float* h_hi = out;                               // staged in d_out

        hipMemsetAsync(cursor, 0, (size_t)NN * 4, stream);
        k_hist<<<eb, 256, 0, stream>>>(ei, cursor);
        k_scan_bsum<<<NB_SCAN, SCAN_B, 0, stream>>>(cursor, bsum);
        k_scan_top<<<1, SCAN_B, 0, stream>>>(bsum, NB_SCAN);
        k_scan_final<<<NB_SCAN, SCAN_B, 0, stream>>>(cursor, bsum);
        k_fill<<<eb, 256, 0, stream>>>(ei, cursor, srt);
        k_layer1<<<nb, 256, 0, stream>>>(x, cursor, srt, Wrel1, Wroot1, b1, h_hi, h_lo);
        k_layer2<<<nb, 256, 0, stream>>>(h_hi, h_lo, cursor, srt, Wrel2, Wroot2, b2, best);
        k_onehot<<<nb, 256, 0, stream>>>(best, out);
    } else {
        // fallback: proven round-2 atomic path (needs 48 MB ws)
        double* agg = (double*)d_ws;
        const size_t aggBytes = (size_t)NN * F * sizeof(double);
        float* h1f = out;
        hipMemsetAsync(agg, 0, aggBytes, stream);
        k_scatter_x<<<eb, 256, 0, stream>>>(x, ei, agg);
        k_lin1_f<<<nb, 256, 0, stream>>>(x, agg, Wrel1, Wroot1, b1, h1f);
        hipMemsetAsync(agg, 0, aggBytes, stream);
        k_scatter_h32<<<eb, 256, 0, stream>>>(h1f, ei, agg);
        k_lin2_f<<<nb, 256, 0, stream>>>(h1f, agg, Wrel2, Wroot2, b2, out);
    }
}

// Round 4
// 1443.241 us; speedup vs baseline: 5.9718x; 2.0147x over previous
//
#include <hip/hip_runtime.h>

static constexpr int       NN   = 1000000;
static constexpr long long NE   = 16000000;
static constexpr int       F    = 6;
static constexpr int       BSH  = 10;                 // 1024 nodes per bucket
static constexpr int       BNOD = 1 << BSH;           // 1024
static constexpr int       NBUCK = (NN + BNOD - 1) / BNOD;   // 977
static constexpr int       NPART = 256;               // partition blocks
static constexpr long long CHUNK = NE / NPART;        // 62500 exactly
static constexpr int       SCANN = NBUCK * NPART;     // 250112
static constexpr int       SCAN_B = 256;

// ---------------------------------------------------------------------------
// Phase A: per-(bucket, partition-block) histogram. bh is bucket-major.
// ---------------------------------------------------------------------------
__global__ __launch_bounds__(256) void k_bhist(
    const int* __restrict__ ei, int* __restrict__ bh)
{
    __shared__ int h[NBUCK];
    int t = threadIdx.x, blk = blockIdx.x;
    for (int i = t; i < NBUCK; i += 256) h[i] = 0;
    __syncthreads();
    long long e0 = (long long)blk * CHUNK, e1 = e0 + CHUNK;
    for (long long e = e0 + t; e < e1; e += 256)
        atomicAdd(&h[ei[NE + e] >> BSH], 1);
    __syncthreads();
    for (int i = t; i < NBUCK; i += 256) bh[i * NPART + blk] = h[i];
}

// ---------------------------------------------------------------------------
// Exclusive scan over n ints (two-level, n-parameterized)
// ---------------------------------------------------------------------------
__global__ __launch_bounds__(SCAN_B) void k_scan_bsum(
    const int* __restrict__ a, int* __restrict__ bsum, int n)
{
    __shared__ int s[SCAN_B];
    int i = blockIdx.x * SCAN_B + threadIdx.x;
    s[threadIdx.x] = (i < n) ? a[i] : 0;
    __syncthreads();
    for (int off = SCAN_B / 2; off > 0; off >>= 1) {
        if (threadIdx.x < off) s[threadIdx.x] += s[threadIdx.x + off];
        __syncthreads();
    }
    if (threadIdx.x == 0) bsum[blockIdx.x] = s[0];
}

__global__ __launch_bounds__(SCAN_B) void k_scan_top(int* __restrict__ bsum, int n)
{
    __shared__ int s[SCAN_B];
    __shared__ int carry;
    if (threadIdx.x == 0) carry = 0;
    __syncthreads();
    for (int base = 0; base < n; base += SCAN_B) {
        int i = base + threadIdx.x;
        int v = (i < n) ? bsum[i] : 0;
        s[threadIdx.x] = v;
        __syncthreads();
        for (int off = 1; off < SCAN_B; off <<= 1) {
            int tv = (threadIdx.x >= off) ? s[threadIdx.x - off] : 0;
            __syncthreads();
            s[threadIdx.x] += tv;
            __syncthreads();
        }
        int incl = s[threadIdx.x];
        int total = s[SCAN_B - 1];
        if (i < n) bsum[i] = incl - v + carry;
        __syncthreads();
        if (threadIdx.x == 0) carry += total;
        __syncthreads();
    }
}

__global__ __launch_bounds__(SCAN_B) void k_scan_final(
    int* __restrict__ a, const int* __restrict__ bsum, int n)
{
    __shared__ int s[SCAN_B];
    int i = blockIdx.x * SCAN_B + threadIdx.x;
    int v = (i < n) ? a[i] : 0;
    s[threadIdx.x] = v;
    __syncthreads();
    for (int off = 1; off < SCAN_B; off <<= 1) {
        int tv = (threadIdx.x >= off) ? s[threadIdx.x - off] : 0;
        __syncthreads();
        s[threadIdx.x] += tv;
        __syncthreads();
    }
    if (i < n) a[i] = s[threadIdx.x] - v + bsum[blockIdx.x];
}

// ---------------------------------------------------------------------------
// Phase B: partition edges into bucket regions. Same chunking as k_bhist.
// Each (bucket,block) run is contiguous -> sector-efficient writes.
// ---------------------------------------------------------------------------
__global__ __launch_bounds__(256) void k_partition(
    const int* __restrict__ ei, const int* __restrict__ scan,
    unsigned int* __restrict__ pairs)
{
    __shared__ int cur[NBUCK];
    int t = threadIdx.x, blk = blockIdx.x;
    for (int i = t; i < NBUCK; i += 256) cur[i] = scan[i * NPART + blk];
    __syncthreads();
    long long e0 = (long long)blk * CHUNK, e1 = e0 + CHUNK;
    for (long long e = e0 + t; e < e1; e += 256) {
        int s = ei[e];
        int d = ei[NE + e];
        int b = d >> BSH;
        int pos = atomicAdd(&cur[b], 1);
        pairs[pos] = ((unsigned)s << BSH) | (unsigned)(d & (BNOD - 1));
    }
}

// ---------------------------------------------------------------------------
// Layer 1: one block per bucket; fp64 accumulation in LDS; h1 -> hi/lo floats
// ---------------------------------------------------------------------------
__global__ __launch_bounds__(256) void k_layer1(
    const float* __restrict__ x, const int* __restrict__ scan,
    const unsigned int* __restrict__ pairs,
    const float* __restrict__ Wrel, const float* __restrict__ Wroot,
    const float* __restrict__ bias,
    float* __restrict__ h_hi, float* __restrict__ h_lo)
{
    __shared__ double sAcc[BNOD * F];           // 48 KB
    __shared__ double sR[F * F], sT[F * F], sB[F];
    int t = threadIdx.x, b = blockIdx.x;
    if (t < F * F) { sR[t] = (double)Wrel[t]; sT[t] = (double)Wroot[t]; }
    if (t < F) sB[t] = (double)bias[t];
    for (int i = t; i < BNOD * F; i += 256) sAcc[i] = 0.0;
    __syncthreads();

    long long p0 = scan[b * NPART];
    long long p1 = (b == NBUCK - 1) ? NE : (long long)scan[(b + 1) * NPART];
    for (long long p = p0 + t; p < p1; p += 256) {
        unsigned v = pairs[p];
        int s  = (int)(v >> BSH);
        int dl = (int)(v & (BNOD - 1));
        const float* xr = x + (long long)s * F;
        float2 a = *(const float2*)(xr + 0);
        float2 bb = *(const float2*)(xr + 2);
        float2 c = *(const float2*)(xr + 4);
        double* ap = sAcc + dl * F;
        unsafeAtomicAdd(ap + 0, (double)a.x);
        unsafeAtomicAdd(ap + 1, (double)a.y);
        unsafeAtomicAdd(ap + 2, (double)bb.x);
        unsafeAtomicAdd(ap + 3, (double)bb.y);
        unsafeAtomicAdd(ap + 4, (double)c.x);
        unsafeAtomicAdd(ap + 5, (double)c.y);
    }
    __syncthreads();

    int nodeBase = b << BSH;
    int numNodes = (NN - nodeBase < BNOD) ? (NN - nodeBase) : BNOD;
    for (int n = t; n < numNodes; n += 256) {
        long long i = nodeBase + n;
        const double* ac = sAcc + n * F;
        const float* xi = x + i * F;
        double xv[F];
        #pragma unroll
        for (int j = 0; j < F; ++j) xv[j] = (double)xi[j];
        float* hh = h_hi + i * F;
        float* hl = h_lo + i * F;
        #pragma unroll
        for (int k = 0; k < F; ++k) {
            double h = sB[k];
            #pragma unroll
            for (int j = 0; j < F; ++j)
                h += ac[j] * sR[k * F + j] + xv[j] * sT[k * F + j];
            float hi = (float)h;
            hh[k] = hi;
            hl[k] = (float)(h - (double)hi);
        }
    }
}

// ---------------------------------------------------------------------------
// Layer 2: same structure; gathers h1 hi/lo pairs; argmax -> best byte
// ---------------------------------------------------------------------------
__global__ __launch_bounds__(256) void k_layer2(
    const float* __restrict__ h_hi, const float* __restrict__ h_lo,
    const int* __restrict__ scan, const unsigned int* __restrict__ pairs,
    const float* __restrict__ Wrel, const float* __restrict__ Wroot,
    const float* __restrict__ bias, unsigned char* __restrict__ best)
{
    __shared__ double sAcc[BNOD * F];
    __shared__ double sR[F * F], sT[F * F], sB[F];
    int t = threadIdx.x, b = blockIdx.x;
    if (t < F * F) { sR[t] = (double)Wrel[t]; sT[t] = (double)Wroot[t]; }
    if (t < F) sB[t] = (double)bias[t];
    for (int i = t; i < BNOD * F; i += 256) sAcc[i] = 0.0;
    __syncthreads();

    long long p0 = scan[b * NPART];
    long long p1 = (b == NBUCK - 1) ? NE : (long long)scan[(b + 1) * NPART];
    for (long long p = p0 + t; p < p1; p += 256) {
        unsigned v = pairs[p];
        long long r = (long long)(v >> BSH) * F;
        int dl = (int)(v & (BNOD - 1));
        float2 a  = *(const float2*)(h_hi + r + 0);
        float2 bb = *(const float2*)(h_hi + r + 2);
        float2 c  = *(const float2*)(h_hi + r + 4);
        float2 la = *(const float2*)(h_lo + r + 0);
        float2 lb = *(const float2*)(h_lo + r + 2);
        float2 lc = *(const float2*)(h_lo + r + 4);
        double* ap = sAcc + dl * F;
        unsafeAtomicAdd(ap + 0, (double)a.x + (double)la.x);
        unsafeAtomicAdd(ap + 1, (double)a.y + (double)la.y);
        unsafeAtomicAdd(ap + 2, (double)bb.x + (double)lb.x);
        unsafeAtomicAdd(ap + 3, (double)bb.y + (double)lb.y);
        unsafeAtomicAdd(ap + 4, (double)c.x + (double)lc.x);
        unsafeAtomicAdd(ap + 5, (double)c.y + (double)lc.y);
    }
    __syncthreads();

    int nodeBase = b << BSH;
    int numNodes = (NN - nodeBase < BNOD) ? (NN - nodeBase) : BNOD;
    for (int n = t; n < numNodes; n += 256) {
        long long i = nodeBase + n;
        const double* ac = sAcc + n * F;
        long long ri = i * F;
        double hv[F];
        #pragma unroll
        for (int j = 0; j < F; ++j)
            hv[j] = (double)h_hi[ri + j] + (double)h_lo[ri + j];
        double h2[F];
        #pragma unroll
        for (int k = 0; k < F; ++k) {
            double h = sB[k];
            #pragma unroll
            for (int j = 0; j < F; ++j)
                h += ac[j] * sR[k * F + j] + hv[j] * sT[k * F + j];
            h2[k] = h;
        }
        int bi = 0;
        double bv = h2[0];
        #pragma unroll
        for (int k = 1; k < F; ++k)
            if (h2[k] > bv) { bv = h2[k]; bi = k; }
        best[i] = (unsigned char)bi;
    }
}

// K6: expand one-hot
__global__ __launch_bounds__(256) void k_onehot(
    const unsigned char* __restrict__ best, float* __restrict__ out)
{
    int i = blockIdx.x * blockDim.x + threadIdx.x;
    if (i >= NN) return;
    int b = best[i];
    float* o = out + (long long)i * F;
    #pragma unroll
    for (int k = 0; k < F; ++k) o[k] = (k == b) ? 1.0f : 0.0f;
}

// ===================== round-2 fallback (atomic path) =======================
__global__ __launch_bounds__(256) void k_scatter_x(
    const float* __restrict__ x, const int* __restrict__ ei,
    double* __restrict__ agg)
{
    long long e = (long long)blockIdx.x * blockDim.x + threadIdx.x;
    if (e >= NE) return;
    int s = ei[e], d = ei[NE + e];
    const float* xr = x + (long long)s * F;
    double* ar = agg + (long long)d * F;
    float2 a = *(const float2*)(xr + 0);
    float2 b = *(const float2*)(xr + 2);
    float2 c = *(const float2*)(xr + 4);
    unsafeAtomicAdd(ar + 0, (double)a.x);
    unsafeAtomicAdd(ar + 1, (double)a.y);
    unsafeAtomicAdd(ar + 2, (double)b.x);
    unsafeAtomicAdd(ar + 3, (double)b.y);
    unsafeAtomicAdd(ar + 4, (double)c.x);
    unsafeAtomicAdd(ar + 5, (double)c.y);
}

__global__ __launch_bounds__(256) void k_lin1_f(
    const float* __restrict__ x, const double* __restrict__ agg,
    const float* __restrict__ Wrel, const float* __restrict__ Wroot,
    const float* __restrict__ bias, float* __restrict__ h)
{
    __shared__ double sR[F * F], sT[F * F], sB[F];
    int t = threadIdx.x;
    if (t < F * F) { sR[t] = (double)Wrel[t]; sT[t] = (double)Wroot[t]; }
    if (t < F) sB[t] = (double)bias[t];
    __syncthreads();
    long long i = (long long)blockIdx.x * blockDim.x + t;
    if (i >= NN) return;
    const float*  xr = x + i * F;
    const double* ar = agg + i * F;
    double xv[F], av[F];
    #pragma unroll
    for (int j = 0; j < F; ++j) { xv[j] = (double)xr[j]; av[j] = ar[j]; }
    float* hr = h + i * F;
    #pragma unroll
    for (int k = 0; k < F; ++k) {
        double a = sB[k];
        #pragma unroll
        for (int j = 0; j < F; ++j)
            a += av[j] * sR[k * F + j] + xv[j] * sT[k * F + j];
        hr[k] = (float)a;
    }
}

__global__ __launch_bounds__(256) void k_scatter_h32(
    const float* __restrict__ h, const int* __restrict__ ei,
    double* __restrict__ agg)
{
    long long e = (long long)blockIdx.x * blockDim.x + threadIdx.x;
    if (e >= NE) return;
    int s = ei[e], d = ei[NE + e];
    const float* hr = h + (long long)s * F;
    double* ar = agg + (long long)d * F;
    float2 a = *(const float2*)(hr + 0);
    float2 b = *(const float2*)(hr + 2);
    float2 c = *(const float2*)(hr + 4);
    unsafeAtomicAdd(ar + 0, (double)a.x);
    unsafeAtomicAdd(ar + 1, (double)a.y);
    unsafeAtomicAdd(ar + 2, (double)b.x);
    unsafeAtomicAdd(ar + 3, (double)b.y);
    unsafeAtomicAdd(ar + 4, (double)c.x);
    unsafeAtomicAdd(ar + 5, (double)c.y);
}

__global__ __launch_bounds__(256) void k_lin2_f(
    const float* __restrict__ h1, const double* __restrict__ agg,
    const float* __restrict__ Wrel, const float* __restrict__ Wroot,
    const float* __restrict__ bias, float* __restrict__ out)
{
    __shared__ double sR[F * F], sT[F * F], sB[F];
    int t = threadIdx.x;
    if (t < F * F) { sR[t] = (double)Wrel[t]; sT[t] = (double)Wroot[t]; }
    if (t < F) sB[t] = (double)bias[t];
    __syncthreads();
    long long i = (long long)blockIdx.x * blockDim.x + t;
    if (i >= NN) return;
    const float*  hr = h1 + i * F;
    const double* ar = agg + i * F;
    double hv[F], av[F];
    #pragma unroll
    for (int j = 0; j < F; ++j) { hv[j] = (double)hr[j]; av[j] = ar[j]; }
    double h2[F];
    #pragma unroll
    for (int k = 0; k < F; ++k) {
        double a = sB[k];
        #pragma unroll
        for (int j = 0; j < F; ++j)
            a += av[j] * sR[k * F + j] + hv[j] * sT[k * F + j];
        h2[k] = a;
    }
    int b = 0;
    double bv = h2[0];
    #pragma unroll
    for (int k = 1; k < F; ++k)
        if (h2[k] > bv) { bv = h2[k]; b = k; }
    float* o = out + i * F;
    #pragma unroll
    for (int k = 0; k < F; ++k) o[k] = (k == b) ? 1.0f : 0.0f;
}

// ============================================================================
extern "C" void kernel_launch(void* const* d_in, const int* in_sizes, int n_in,
                              void* d_out, int out_size, void* d_ws, size_t ws_size,
                              hipStream_t stream) {
    const float* x      = (const float*)d_in[0];
    const int*   ei     = (const int*)d_in[1];     // int32 per harness contract
    const float* Wrel1  = (const float*)d_in[2];
    const float* Wroot1 = (const float*)d_in[3];
    const float* b1     = (const float*)d_in[4];
    const float* Wrel2  = (const float*)d_in[5];
    const float* Wroot2 = (const float*)d_in[6];
    const float* b2     = (const float*)d_in[7];
    float* out = (float*)d_out;

    const int nb = (NN + 255) / 256;

    // ws layout
    size_t o_pairs = 0;                                    // u32[16M] = 64 MB
    size_t o_scan  = o_pairs + (size_t)NE * 4;             // int[250112] ~ 1 MB
    size_t o_bsum  = o_scan + (size_t)SCANN * 4;           // int[977+pad]
    size_t o_hlo   = (o_bsum + 4096 + 15) & ~(size_t)15;   // float[6M] = 24 MB
    size_t o_best  = o_hlo + (size_t)NN * F * 4;           // u8[NN] = 1 MB
    size_t need    = o_best + (size_t)NN;

    if (ws_size >= need) {
        char* ws = (char*)d_ws;
        unsigned int* pairs = (unsigned int*)(ws + o_pairs);
        int*   scan  = (int*)(ws + o_scan);
        int*   bsum  = (int*)(ws + o_bsum);
        float* h_lo  = (float*)(ws + o_hlo);
        unsigned char* best = (unsigned char*)(ws + o_best);
        float* h_hi = out;                                 // staged in d_out

        const int scanBlocks = (SCANN + SCAN_B - 1) / SCAN_B;   // 977
        k_bhist<<<NPART, 256, 0, stream>>>(ei, scan);
        k_scan_bsum<<<scanBlocks, SCAN_B, 0, stream>>>(scan, bsum, SCANN);
        k_scan_top<<<1, SCAN_B, 0, stream>>>(bsum, scanBlocks);
        k_scan_final<<<scanBlocks, SCAN_B, 0, stream>>>(scan, bsum, SCANN);
        k_partition<<<NPART, 256, 0, stream>>>(ei, scan, pairs);
        k_layer1<<<NBUCK, 256, 0, stream>>>(x, scan, pairs, Wrel1, Wroot1, b1, h_hi, h_lo);
        k_layer2<<<NBUCK, 256, 0, stream>>>(h_hi, h_lo, scan, pairs, Wrel2, Wroot2, b2, best);
        k_onehot<<<nb, 256, 0, stream>>>(best, out);
    } else {
        // fallback: round-2 atomic path (needs 48 MB ws)
        double* agg = (double*)d_ws;
        const size_t aggBytes = (size_t)NN * F * sizeof(double);
        const int eb = (int)((NE + 255) / 256);
        float* h1f = out;
        hipMemsetAsync(agg, 0, aggBytes, stream);
        k_scatter_x<<<eb, 256, 0, stream>>>(x, ei, agg);
        k_lin1_f<<<nb, 256, 0, stream>>>(x, agg, Wrel1, Wroot1, b1, h1f);
        hipMemsetAsync(agg, 0, aggBytes, stream);
        k_scatter_h32<<<eb, 256, 0, stream>>>(h1f, ei, agg);
        k_lin2_f<<<nb, 256, 0, stream>>>(h1f, agg, Wrel2, Wroot2, b2, out);
    }
}

// Round 5
// 1070.805 us; speedup vs baseline: 8.0489x; 1.3478x over previous
//
#include <hip/hip_runtime.h>

static constexpr int       NN   = 1000000;
static constexpr long long NE   = 16000000;
static constexpr int       F    = 6;
static constexpr int       BSH  = 10;                 // 1024 nodes per bucket
static constexpr int       BNOD = 1 << BSH;
static constexpr int       NBUCK = (NN + BNOD - 1) / BNOD;   // 977
static constexpr int       NPART = 256;
static constexpr long long CHUNK = NE / NPART;        // 62500
static constexpr int       CH4   = (int)(CHUNK / 4);  // 15625
static constexpr int       SCANN = NBUCK * NPART;     // 250112
static constexpr int       SCAN_B = 256;

// ---------------------------------------------------------------------------
// Phase A: per-(bucket, partition-block) histogram (int4 edge loads)
// ---------------------------------------------------------------------------
__global__ __launch_bounds__(256) void k_bhist(
    const int* __restrict__ ei, int* __restrict__ bh)
{
    __shared__ int h[NBUCK];
    int t = threadIdx.x, blk = blockIdx.x;
    for (int i = t; i < NBUCK; i += 256) h[i] = 0;
    __syncthreads();
    const int4* d4 = (const int4*)(ei + NE + (long long)blk * CHUNK);
    for (int idx = t; idx < CH4; idx += 256) {
        int4 d = d4[idx];
        atomicAdd(&h[d.x >> BSH], 1);
        atomicAdd(&h[d.y >> BSH], 1);
        atomicAdd(&h[d.z >> BSH], 1);
        atomicAdd(&h[d.w >> BSH], 1);
    }
    __syncthreads();
    for (int i = t; i < NBUCK; i += 256) bh[i * NPART + blk] = h[i];
}

// ---------------------------------------------------------------------------
// Exclusive scan (two-level)
// ---------------------------------------------------------------------------
__global__ __launch_bounds__(SCAN_B) void k_scan_bsum(
    const int* __restrict__ a, int* __restrict__ bsum, int n)
{
    __shared__ int s[SCAN_B];
    int i = blockIdx.x * SCAN_B + threadIdx.x;
    s[threadIdx.x] = (i < n) ? a[i] : 0;
    __syncthreads();
    for (int off = SCAN_B / 2; off > 0; off >>= 1) {
        if (threadIdx.x < off) s[threadIdx.x] += s[threadIdx.x + off];
        __syncthreads();
    }
    if (threadIdx.x == 0) bsum[blockIdx.x] = s[0];
}

__global__ __launch_bounds__(SCAN_B) void k_scan_top(int* __restrict__ bsum, int n)
{
    __shared__ int s[SCAN_B];
    __shared__ int carry;
    if (threadIdx.x == 0) carry = 0;
    __syncthreads();
    for (int base = 0; base < n; base += SCAN_B) {
        int i = base + threadIdx.x;
        int v = (i < n) ? bsum[i] : 0;
        s[threadIdx.x] = v;
        __syncthreads();
        for (int off = 1; off < SCAN_B; off <<= 1) {
            int tv = (threadIdx.x >= off) ? s[threadIdx.x - off] : 0;
            __syncthreads();
            s[threadIdx.x] += tv;
            __syncthreads();
        }
        int incl = s[threadIdx.x];
        int total = s[SCAN_B - 1];
        if (i < n) bsum[i] = incl - v + carry;
        __syncthreads();
        if (threadIdx.x == 0) carry += total;
        __syncthreads();
    }
}

__global__ __launch_bounds__(SCAN_B) void k_scan_final(
    int* __restrict__ a, const int* __restrict__ bsum, int n)
{
    __shared__ int s[SCAN_B];
    int i = blockIdx.x * SCAN_B + threadIdx.x;
    int v = (i < n) ? a[i] : 0;
    s[threadIdx.x] = v;
    __syncthreads();
    for (int off = 1; off < SCAN_B; off <<= 1) {
        int tv = (threadIdx.x >= off) ? s[threadIdx.x - off] : 0;
        __syncthreads();
        s[threadIdx.x] += tv;
        __syncthreads();
    }
    if (i < n) a[i] = s[threadIdx.x] - v + bsum[blockIdx.x];
}

// ---------------------------------------------------------------------------
// Phase B: partition edges into bucket regions (int4 loads)
// ---------------------------------------------------------------------------
__global__ __launch_bounds__(256) void k_partition(
    const int* __restrict__ ei, const int* __restrict__ scan,
    unsigned int* __restrict__ pairs)
{
    __shared__ int cur[NBUCK];
    int t = threadIdx.x, blk = blockIdx.x;
    for (int i = t; i < NBUCK; i += 256) cur[i] = scan[i * NPART + blk];
    __syncthreads();
    const int4* s4 = (const int4*)(ei + (long long)blk * CHUNK);
    const int4* d4 = (const int4*)(ei + NE + (long long)blk * CHUNK);
    for (int idx = t; idx < CH4; idx += 256) {
        int4 s = s4[idx];
        int4 d = d4[idx];
        int p;
        p = atomicAdd(&cur[d.x >> BSH], 1);
        pairs[p] = ((unsigned)s.x << BSH) | (unsigned)(d.x & (BNOD - 1));
        p = atomicAdd(&cur[d.y >> BSH], 1);
        pairs[p] = ((unsigned)s.y << BSH) | (unsigned)(d.y & (BNOD - 1));
        p = atomicAdd(&cur[d.z >> BSH], 1);
        pairs[p] = ((unsigned)s.z << BSH) | (unsigned)(d.z & (BNOD - 1));
        p = atomicAdd(&cur[d.w >> BSH], 1);
        pairs[p] = ((unsigned)s.w << BSH) | (unsigned)(d.w & (BNOD - 1));
    }
}

// ---------------------------------------------------------------------------
// x -> xp: pad rows to 32 B (8 floats) so every gather is one aligned sector
// ---------------------------------------------------------------------------
__global__ __launch_bounds__(256) void k_xpad(
    const float* __restrict__ x, float* __restrict__ xp)
{
    int i = blockIdx.x * blockDim.x + threadIdx.x;
    if (i >= NN) return;
    const float* xr = x + (long long)i * F;
    float2 a = *(const float2*)(xr + 0);
    float2 b = *(const float2*)(xr + 2);
    float2 c = *(const float2*)(xr + 4);
    float4* o = (float4*)(xp + ((long long)i << 3));
    o[0] = make_float4(a.x, a.y, b.x, b.y);
    o[1] = make_float4(c.x, c.y, 0.0f, 0.0f);
}

// ---------------------------------------------------------------------------
// Layer 1 (padded): gather xp (1 sector/edge), LDS fp64 accum,
// h1 -> padded 64 B double rows (h1p)
// ---------------------------------------------------------------------------
__global__ __launch_bounds__(256) void k_layer1p(
    const float* __restrict__ xp, const int* __restrict__ scan,
    const unsigned int* __restrict__ pairs,
    const float* __restrict__ Wrel, const float* __restrict__ Wroot,
    const float* __restrict__ bias, double* __restrict__ h1p)
{
    __shared__ double sAcc[BNOD * F];           // 48 KB
    __shared__ double sR[F * F], sT[F * F], sB[F];
    int t = threadIdx.x, b = blockIdx.x;
    if (t < F * F) { sR[t] = (double)Wrel[t]; sT[t] = (double)Wroot[t]; }
    if (t < F) sB[t] = (double)bias[t];
    for (int i = t; i < BNOD * F; i += 256) sAcc[i] = 0.0;
    __syncthreads();

    long long p0 = scan[b * NPART];
    long long p1 = (b == NBUCK - 1) ? NE : (long long)scan[(b + 1) * NPART];
    for (long long p = p0 + t; p < p1; p += 256) {
        unsigned v = pairs[p];
        const float4* xr = (const float4*)(xp + ((long long)(v >> BSH) << 3));
        float4 a = xr[0];
        float4 c = xr[1];
        double* ap = sAcc + (v & (BNOD - 1)) * F;
        unsafeAtomicAdd(ap + 0, (double)a.x);
        unsafeAtomicAdd(ap + 1, (double)a.y);
        unsafeAtomicAdd(ap + 2, (double)a.z);
        unsafeAtomicAdd(ap + 3, (double)a.w);
        unsafeAtomicAdd(ap + 4, (double)c.x);
        unsafeAtomicAdd(ap + 5, (double)c.y);
    }
    __syncthreads();

    int nodeBase = b << BSH;
    int numNodes = (NN - nodeBase < BNOD) ? (NN - nodeBase) : BNOD;
    for (int n = t; n < numNodes; n += 256) {
        long long i = nodeBase + n;
        const double* ac = sAcc + n * F;
        const float4* xr = (const float4*)(xp + (i << 3));
        float4 a = xr[0];
        float4 c = xr[1];
        double xv[F] = {(double)a.x, (double)a.y, (double)a.z,
                        (double)a.w, (double)c.x, (double)c.y};
        double hv[F];
        #pragma unroll
        for (int k = 0; k < F; ++k) {
            double h = sB[k];
            #pragma unroll
            for (int j = 0; j < F; ++j)
                h += ac[j] * sR[k * F + j] + xv[j] * sT[k * F + j];
            hv[k] = h;
        }
        double* hr = h1p + (i << 3);
        *(double2*)(hr + 0) = make_double2(hv[0], hv[1]);
        *(double2*)(hr + 2) = make_double2(hv[2], hv[3]);
        *(double2*)(hr + 4) = make_double2(hv[4], hv[5]);
    }
}

// ---------------------------------------------------------------------------
// Layer 2 (padded): gather h1p (1 sector/edge), LDS fp64 accum,
// argmax -> one-hot written directly to out
// ---------------------------------------------------------------------------
__global__ __launch_bounds__(256) void k_layer2p(
    const double* __restrict__ h1p, const int* __restrict__ scan,
    const unsigned int* __restrict__ pairs,
    const float* __restrict__ Wrel, const float* __restrict__ Wroot,
    const float* __restrict__ bias, float* __restrict__ out)
{
    __shared__ double sAcc[BNOD * F];
    __shared__ double sR[F * F], sT[F * F], sB[F];
    int t = threadIdx.x, b = blockIdx.x;
    if (t < F * F) { sR[t] = (double)Wrel[t]; sT[t] = (double)Wroot[t]; }
    if (t < F) sB[t] = (double)bias[t];
    for (int i = t; i < BNOD * F; i += 256) sAcc[i] = 0.0;
    __syncthreads();

    long long p0 = scan[b * NPART];
    long long p1 = (b == NBUCK - 1) ? NE : (long long)scan[(b + 1) * NPART];
    for (long long p = p0 + t; p < p1; p += 256) {
        unsigned v = pairs[p];
        const double* hr = h1p + ((long long)(v >> BSH) << 3);
        double2 d01 = *(const double2*)(hr + 0);
        double2 d23 = *(const double2*)(hr + 2);
        double2 d45 = *(const double2*)(hr + 4);
        double* ap = sAcc + (v & (BNOD - 1)) * F;
        unsafeAtomicAdd(ap + 0, d01.x);
        unsafeAtomicAdd(ap + 1, d01.y);
        unsafeAtomicAdd(ap + 2, d23.x);
        unsafeAtomicAdd(ap + 3, d23.y);
        unsafeAtomicAdd(ap + 4, d45.x);
        unsafeAtomicAdd(ap + 5, d45.y);
    }
    __syncthreads();

    int nodeBase = b << BSH;
    int numNodes = (NN - nodeBase < BNOD) ? (NN - nodeBase) : BNOD;
    for (int n = t; n < numNodes; n += 256) {
        long long i = nodeBase + n;
        const double* ac = sAcc + n * F;
        const double* hr = h1p + (i << 3);
        double h2[F];
        #pragma unroll
        for (int k = 0; k < F; ++k) {
            double h = sB[k];
            #pragma unroll
            for (int j = 0; j < F; ++j)
                h += ac[j] * sR[k * F + j] + hr[j] * sT[k * F + j];
            h2[k] = h;
        }
        int bi = 0;
        double bv = h2[0];
        #pragma unroll
        for (int k = 1; k < F; ++k)
            if (h2[k] > bv) { bv = h2[k]; bi = k; }
        float o[F];
        #pragma unroll
        for (int k = 0; k < F; ++k) o[k] = (k == bi) ? 1.0f : 0.0f;
        float2* op = (float2*)(out + i * F);
        op[0] = make_float2(o[0], o[1]);
        op[1] = make_float2(o[2], o[3]);
        op[2] = make_float2(o[4], o[5]);
    }
}

// ===================== tier B: round-4 proven path ==========================
__global__ __launch_bounds__(256) void k_layer1(
    const float* __restrict__ x, const int* __restrict__ scan,
    const unsigned int* __restrict__ pairs,
    const float* __restrict__ Wrel, const float* __restrict__ Wroot,
    const float* __restrict__ bias,
    float* __restrict__ h_hi, float* __restrict__ h_lo)
{
    __shared__ double sAcc[BNOD * F];
    __shared__ double sR[F * F], sT[F * F], sB[F];
    int t = threadIdx.x, b = blockIdx.x;
    if (t < F * F) { sR[t] = (double)Wrel[t]; sT[t] = (double)Wroot[t]; }
    if (t < F) sB[t] = (double)bias[t];
    for (int i = t; i < BNOD * F; i += 256) sAcc[i] = 0.0;
    __syncthreads();
    long long p0 = scan[b * NPART];
    long long p1 = (b == NBUCK - 1) ? NE : (long long)scan[(b + 1) * NPART];
    for (long long p = p0 + t; p < p1; p += 256) {
        unsigned v = pairs[p];
        const float* xr = x + (long long)(v >> BSH) * F;
        float2 a = *(const float2*)(xr + 0);
        float2 bb = *(const float2*)(xr + 2);
        float2 c = *(const float2*)(xr + 4);
        double* ap = sAcc + (v & (BNOD - 1)) * F;
        unsafeAtomicAdd(ap + 0, (double)a.x);
        unsafeAtomicAdd(ap + 1, (double)a.y);
        unsafeAtomicAdd(ap + 2, (double)bb.x);
        unsafeAtomicAdd(ap + 3, (double)bb.y);
        unsafeAtomicAdd(ap + 4, (double)c.x);
        unsafeAtomicAdd(ap + 5, (double)c.y);
    }
    __syncthreads();
    int nodeBase = b << BSH;
    int numNodes = (NN - nodeBase < BNOD) ? (NN - nodeBase) : BNOD;
    for (int n = t; n < numNodes; n += 256) {
        long long i = nodeBase + n;
        const double* ac = sAcc + n * F;
        const float* xi = x + i * F;
        double xv[F];
        #pragma unroll
        for (int j = 0; j < F; ++j) xv[j] = (double)xi[j];
        float* hh = h_hi + i * F;
        float* hl = h_lo + i * F;
        #pragma unroll
        for (int k = 0; k < F; ++k) {
            double h = sB[k];
            #pragma unroll
            for (int j = 0; j < F; ++j)
                h += ac[j] * sR[k * F + j] + xv[j] * sT[k * F + j];
            float hi = (float)h;
            hh[k] = hi;
            hl[k] = (float)(h - (double)hi);
        }
    }
}

__global__ __launch_bounds__(256) void k_layer2(
    const float* __restrict__ h_hi, const float* __restrict__ h_lo,
    const int* __restrict__ scan, const unsigned int* __restrict__ pairs,
    const float* __restrict__ Wrel, const float* __restrict__ Wroot,
    const float* __restrict__ bias, unsigned char* __restrict__ best)
{
    __shared__ double sAcc[BNOD * F];
    __shared__ double sR[F * F], sT[F * F], sB[F];
    int t = threadIdx.x, b = blockIdx.x;
    if (t < F * F) { sR[t] = (double)Wrel[t]; sT[t] = (double)Wroot[t]; }
    if (t < F) sB[t] = (double)bias[t];
    for (int i = t; i < BNOD * F; i += 256) sAcc[i] = 0.0;
    __syncthreads();
    long long p0 = scan[b * NPART];
    long long p1 = (b == NBUCK - 1) ? NE : (long long)scan[(b + 1) * NPART];
    for (long long p = p0 + t; p < p1; p += 256) {
        unsigned v = pairs[p];
        long long r = (long long)(v >> BSH) * F;
        int dl = (int)(v & (BNOD - 1));
        float2 a  = *(const float2*)(h_hi + r + 0);
        float2 bb = *(const float2*)(h_hi + r + 2);
        float2 c  = *(const float2*)(h_hi + r + 4);
        float2 la = *(const float2*)(h_lo + r + 0);
        float2 lb = *(const float2*)(h_lo + r + 2);
        float2 lc = *(const float2*)(h_lo + r + 4);
        double* ap = sAcc + dl * F;
        unsafeAtomicAdd(ap + 0, (double)a.x + (double)la.x);
        unsafeAtomicAdd(ap + 1, (double)a.y + (double)la.y);
        unsafeAtomicAdd(ap + 2, (double)bb.x + (double)lb.x);
        unsafeAtomicAdd(ap + 3, (double)bb.y + (double)lb.y);
        unsafeAtomicAdd(ap + 4, (double)c.x + (double)lc.x);
        unsafeAtomicAdd(ap + 5, (double)c.y + (double)lc.y);
    }
    __syncthreads();
    int nodeBase = b << BSH;
    int numNodes = (NN - nodeBase < BNOD) ? (NN - nodeBase) : BNOD;
    for (int n = t; n < numNodes; n += 256) {
        long long i = nodeBase + n;
        const double* ac = sAcc + n * F;
        long long ri = i * F;
        double hv[F];
        #pragma unroll
        for (int j = 0; j < F; ++j)
            hv[j] = (double)h_hi[ri + j] + (double)h_lo[ri + j];
        double h2[F];
        #pragma unroll
        for (int k = 0; k < F; ++k) {
            double h = sB[k];
            #pragma unroll
            for (int j = 0; j < F; ++j)
                h += ac[j] * sR[k * F + j] + hv[j] * sT[k * F + j];
            h2[k] = h;
        }
        int bi = 0;
        double bv = h2[0];
        #pragma unroll
        for (int k = 1; k < F; ++k)
            if (h2[k] > bv) { bv = h2[k]; bi = k; }
        best[i] = (unsigned char)bi;
    }
}

__global__ __launch_bounds__(256) void k_onehot(
    const unsigned char* __restrict__ best, float* __restrict__ out)
{
    int i = blockIdx.x * blockDim.x + threadIdx.x;
    if (i >= NN) return;
    int b = best[i];
    float* o = out + (long long)i * F;
    #pragma unroll
    for (int k = 0; k < F; ++k) o[k] = (k == b) ? 1.0f : 0.0f;
}

// ===================== tier C: atomic fallback ==============================
__global__ __launch_bounds__(256) void k_scatter_x(
    const float* __restrict__ x, const int* __restrict__ ei,
    double* __restrict__ agg)
{
    long long e = (long long)blockIdx.x * blockDim.x + threadIdx.x;
    if (e >= NE) return;
    int s = ei[e], d = ei[NE + e];
    const float* xr = x + (long long)s * F;
    double* ar = agg + (long long)d * F;
    float2 a = *(const float2*)(xr + 0);
    float2 b = *(const float2*)(xr + 2);
    float2 c = *(const float2*)(xr + 4);
    unsafeAtomicAdd(ar + 0, (double)a.x);
    unsafeAtomicAdd(ar + 1, (double)a.y);
    unsafeAtomicAdd(ar + 2, (double)b.x);
    unsafeAtomicAdd(ar + 3, (double)b.y);
    unsafeAtomicAdd(ar + 4, (double)c.x);
    unsafeAtomicAdd(ar + 5, (double)c.y);
}

__global__ __launch_bounds__(256) void k_lin1_f(
    const float* __restrict__ x, const double* __restrict__ agg,
    const float* __restrict__ Wrel, const float* __restrict__ Wroot,
    const float* __restrict__ bias, float* __restrict__ h)
{
    __shared__ double sR[F * F], sT[F * F], sB[F];
    int t = threadIdx.x;
    if (t < F * F) { sR[t] = (double)Wrel[t]; sT[t] = (double)Wroot[t]; }
    if (t < F) sB[t] = (double)bias[t];
    __syncthreads();
    long long i = (long long)blockIdx.x * blockDim.x + t;
    if (i >= NN) return;
    const float*  xr = x + i * F;
    const double* ar = agg + i * F;
    double xv[F], av[F];
    #pragma unroll
    for (int j = 0; j < F; ++j) { xv[j] = (double)xr[j]; av[j] = ar[j]; }
    float* hr = h + i * F;
    #pragma unroll
    for (int k = 0; k < F; ++k) {
        double a = sB[k];
        #pragma unroll
        for (int j = 0; j < F; ++j)
            a += av[j] * sR[k * F + j] + xv[j] * sT[k * F + j];
        hr[k] = (float)a;
    }
}

__global__ __launch_bounds__(256) void k_scatter_h32(
    const float* __restrict__ h, const int* __restrict__ ei,
    double* __restrict__ agg)
{
    long long e = (long long)blockIdx.x * blockDim.x + threadIdx.x;
    if (e >= NE) return;
    int s = ei[e], d = ei[NE + e];
    const float* hr = h + (long long)s * F;
    double* ar = agg + (long long)d * F;
    float2 a = *(const float2*)(hr + 0);
    float2 b = *(const float2*)(hr + 2);
    float2 c = *(const float2*)(hr + 4);
    unsafeAtomicAdd(ar + 0, (double)a.x);
    unsafeAtomicAdd(ar + 1, (double)a.y);
    unsafeAtomicAdd(ar + 2, (double)b.x);
    unsafeAtomicAdd(ar + 3, (double)b.y);
    unsafeAtomicAdd(ar + 4, (double)c.x);
    unsafeAtomicAdd(ar + 5, (double)c.y);
}

__global__ __launch_bounds__(256) void k_lin2_f(
    const float* __restrict__ h1, const double* __restrict__ agg,
    const float* __restrict__ Wrel, const float* __restrict__ Wroot,
    const float* __restrict__ bias, float* __restrict__ out)
{
    __shared__ double sR[F * F], sT[F * F], sB[F];
    int t = threadIdx.x;
    if (t < F * F) { sR[t] = (double)Wrel[t]; sT[t] = (double)Wroot[t]; }
    if (t < F) sB[t] = (double)bias[t];
    __syncthreads();
    long long i = (long long)blockIdx.x * blockDim.x + t;
    if (i >= NN) return;
    const float*  hr = h1 + i * F;
    const double* ar = agg + i * F;
    double hv[F], av[F];
    #pragma unroll
    for (int j = 0; j < F; ++j) { hv[j] = (double)hr[j]; av[j] = ar[j]; }
    double h2[F];
    #pragma unroll
    for (int k = 0; k < F; ++k) {
        double a = sB[k];
        #pragma unroll
        for (int j = 0; j < F; ++j)
            a += av[j] * sR[k * F + j] + hv[j] * sT[k * F + j];
        h2[k] = a;
    }
    int b = 0;
    double bv = h2[0];
    #pragma unroll
    for (int k = 1; k < F; ++k)
        if (h2[k] > bv) { bv = h2[k]; b = k; }
    float* o = out + i * F;
    #pragma unroll
    for (int k = 0; k < F; ++k) o[k] = (k == b) ? 1.0f : 0.0f;
}

// ============================================================================
extern "C" void kernel_launch(void* const* d_in, const int* in_sizes, int n_in,
                              void* d_out, int out_size, void* d_ws, size_t ws_size,
                              hipStream_t stream) {
    const float* x      = (const float*)d_in[0];
    const int*   ei     = (const int*)d_in[1];
    const float* Wrel1  = (const float*)d_in[2];
    const float* Wroot1 = (const float*)d_in[3];
    const float* b1     = (const float*)d_in[4];
    const float* Wrel2  = (const float*)d_in[5];
    const float* Wroot2 = (const float*)d_in[6];
    const float* b2     = (const float*)d_in[7];
    float* out = (float*)d_out;

    const int nb = (NN + 255) / 256;
    const int scanBlocks = (SCANN + SCAN_B - 1) / SCAN_B;   // 977

    // ---- tier A+ layout: padded gathers -----------------------------------
    size_t o_pairs = 0;                                    // 64 MB
    size_t o_scan  = o_pairs + (size_t)NE * 4;             // ~1 MB
    size_t o_bsum  = o_scan + (size_t)SCANN * 4;
    size_t o_xp    = (o_bsum + 4096 + 63) & ~(size_t)63;   // 32 MB, 64B-aligned
    size_t o_h1p   = o_xp + (size_t)NN * 8 * 4;            // 64 MB, 64B-aligned
    size_t needA   = o_h1p + (size_t)NN * 8 * 8;           // ~161 MB

    // ---- tier B layout: round-4 hi/lo path --------------------------------
    size_t b_hlo   = (o_bsum + 4096 + 15) & ~(size_t)15;
    size_t b_best  = b_hlo + (size_t)NN * F * 4;
    size_t needB   = b_best + (size_t)NN;                  // ~90 MB

    if (ws_size >= needA) {
        char* ws = (char*)d_ws;
        unsigned int* pairs = (unsigned int*)(ws + o_pairs);
        int*    scan = (int*)(ws + o_scan);
        int*    bsum = (int*)(ws + o_bsum);
        float*  xp   = (float*)(ws + o_xp);
        double* h1p  = (double*)(ws + o_h1p);

        k_bhist<<<NPART, 256, 0, stream>>>(ei, scan);
        k_xpad<<<nb, 256, 0, stream>>>(x, xp);
        k_scan_bsum<<<scanBlocks, SCAN_B, 0, stream>>>(scan, bsum, SCANN);
        k_scan_top<<<1, SCAN_B, 0, stream>>>(bsum, scanBlocks);
        k_scan_final<<<scanBlocks, SCAN_B, 0, stream>>>(scan, bsum, SCANN);
        k_partition<<<NPART, 256, 0, stream>>>(ei, scan, pairs);
        k_layer1p<<<NBUCK, 256, 0, stream>>>(xp, scan, pairs, Wrel1, Wroot1, b1, h1p);
        k_layer2p<<<NBUCK, 256, 0, stream>>>(h1p, scan, pairs, Wrel2, Wroot2, b2, out);
    } else if (ws_size >= needB) {
        char* ws = (char*)d_ws;
        unsigned int* pairs = (unsigned int*)(ws + o_pairs);
        int*   scan  = (int*)(ws + o_scan);
        int*   bsum  = (int*)(ws + o_bsum);
        float* h_lo  = (float*)(ws + b_hlo);
        unsigned char* best = (unsigned char*)(ws + b_best);
        float* h_hi = out;

        k_bhist<<<NPART, 256, 0, stream>>>(ei, scan);
        k_scan_bsum<<<scanBlocks, SCAN_B, 0, stream>>>(scan, bsum, SCANN);
        k_scan_top<<<1, SCAN_B, 0, stream>>>(bsum, scanBlocks);
        k_scan_final<<<scanBlocks, SCAN_B, 0, stream>>>(scan, bsum, SCANN);
        k_partition<<<NPART, 256, 0, stream>>>(ei, scan, pairs);
        k_layer1<<<NBUCK, 256, 0, stream>>>(x, scan, pairs, Wrel1, Wroot1, b1, h_hi, h_lo);
        k_layer2<<<NBUCK, 256, 0, stream>>>(h_hi, h_lo, scan, pairs, Wrel2, Wroot2, b2, best);
        k_onehot<<<nb, 256, 0, stream>>>(best, out);
    } else {
        double* agg = (double*)d_ws;
        const size_t aggBytes = (size_t)NN * F * sizeof(double);
        const int eb = (int)((NE + 255) / 256);
        float* h1f = out;
        hipMemsetAsync(agg, 0, aggBytes, stream);
        k_scatter_x<<<eb, 256, 0, stream>>>(x, ei, agg);
        k_lin1_f<<<nb, 256, 0, stream>>>(x, agg, Wrel1, Wroot1, b1, h1f);
        hipMemsetAsync(agg, 0, aggBytes, stream);
        k_scatter_h32<<<eb, 256, 0, stream>>>(h1f, ei, agg);
        k_lin2_f<<<nb, 256, 0, stream>>>(h1f, agg, Wrel2, Wroot2, b2, out);
    }
}

// Round 6
// 1021.130 us; speedup vs baseline: 8.4405x; 1.0486x over previous
//
#include <hip/hip_runtime.h>

static constexpr int       NN   = 1000000;
static constexpr long long NE   = 16000000;
static constexpr int       F    = 6;
static constexpr int       BSH  = 10;                 // 1024 nodes per bucket
static constexpr int       BNOD = 1 << BSH;
static constexpr int       NBUCK = (NN + BNOD - 1) / BNOD;   // 977
static constexpr int       NPART = 256;
static constexpr long long CHUNK = NE / NPART;        // 62500
static constexpr int       CH4   = (int)(CHUNK / 4);  // 15625
static constexpr int       SCANN = NBUCK * NPART;     // 250112
static constexpr int       SCAN_B = 256;
static constexpr int       SBIN  = 1024;              // src-sort bins (src>>10)

// ---------------------------------------------------------------------------
// Phase A: per-(bucket, partition-block) histogram (int4 edge loads)
// ---------------------------------------------------------------------------
__global__ __launch_bounds__(256) void k_bhist(
    const int* __restrict__ ei, int* __restrict__ bh)
{
    __shared__ int h[NBUCK];
    int t = threadIdx.x, blk = blockIdx.x;
    for (int i = t; i < NBUCK; i += 256) h[i] = 0;
    __syncthreads();
    const int4* d4 = (const int4*)(ei + NE + (long long)blk * CHUNK);
    for (int idx = t; idx < CH4; idx += 256) {
        int4 d = d4[idx];
        atomicAdd(&h[d.x >> BSH], 1);
        atomicAdd(&h[d.y >> BSH], 1);
        atomicAdd(&h[d.z >> BSH], 1);
        atomicAdd(&h[d.w >> BSH], 1);
    }
    __syncthreads();
    for (int i = t; i < NBUCK; i += 256) bh[i * NPART + blk] = h[i];
}

// ---------------------------------------------------------------------------
// Exclusive scan (two-level)
// ---------------------------------------------------------------------------
__global__ __launch_bounds__(SCAN_B) void k_scan_bsum(
    const int* __restrict__ a, int* __restrict__ bsum, int n)
{
    __shared__ int s[SCAN_B];
    int i = blockIdx.x * SCAN_B + threadIdx.x;
    s[threadIdx.x] = (i < n) ? a[i] : 0;
    __syncthreads();
    for (int off = SCAN_B / 2; off > 0; off >>= 1) {
        if (threadIdx.x < off) s[threadIdx.x] += s[threadIdx.x + off];
        __syncthreads();
    }
    if (threadIdx.x == 0) bsum[blockIdx.x] = s[0];
}

__global__ __launch_bounds__(SCAN_B) void k_scan_top(int* __restrict__ bsum, int n)
{
    __shared__ int s[SCAN_B];
    __shared__ int carry;
    if (threadIdx.x == 0) carry = 0;
    __syncthreads();
    for (int base = 0; base < n; base += SCAN_B) {
        int i = base + threadIdx.x;
        int v = (i < n) ? bsum[i] : 0;
        s[threadIdx.x] = v;
        __syncthreads();
        for (int off = 1; off < SCAN_B; off <<= 1) {
            int tv = (threadIdx.x >= off) ? s[threadIdx.x - off] : 0;
            __syncthreads();
            s[threadIdx.x] += tv;
            __syncthreads();
        }
        int incl = s[threadIdx.x];
        int total = s[SCAN_B - 1];
        if (i < n) bsum[i] = incl - v + carry;
        __syncthreads();
        if (threadIdx.x == 0) carry += total;
        __syncthreads();
    }
}

__global__ __launch_bounds__(SCAN_B) void k_scan_final(
    int* __restrict__ a, const int* __restrict__ bsum, int n)
{
    __shared__ int s[SCAN_B];
    int i = blockIdx.x * SCAN_B + threadIdx.x;
    int v = (i < n) ? a[i] : 0;
    s[threadIdx.x] = v;
    __syncthreads();
    for (int off = 1; off < SCAN_B; off <<= 1) {
        int tv = (threadIdx.x >= off) ? s[threadIdx.x - off] : 0;
        __syncthreads();
        s[threadIdx.x] += tv;
        __syncthreads();
    }
    if (i < n) a[i] = s[threadIdx.x] - v + bsum[blockIdx.x];
}

// ---------------------------------------------------------------------------
// Phase B: partition edges into bucket regions (int4 loads)
// ---------------------------------------------------------------------------
__global__ __launch_bounds__(256) void k_partition(
    const int* __restrict__ ei, const int* __restrict__ scan,
    unsigned int* __restrict__ pairs)
{
    __shared__ int cur[NBUCK];
    int t = threadIdx.x, blk = blockIdx.x;
    for (int i = t; i < NBUCK; i += 256) cur[i] = scan[i * NPART + blk];
    __syncthreads();
    const int4* s4 = (const int4*)(ei + (long long)blk * CHUNK);
    const int4* d4 = (const int4*)(ei + NE + (long long)blk * CHUNK);
    for (int idx = t; idx < CH4; idx += 256) {
        int4 s = s4[idx];
        int4 d = d4[idx];
        int p;
        p = atomicAdd(&cur[d.x >> BSH], 1);
        pairs[p] = ((unsigned)s.x << BSH) | (unsigned)(d.x & (BNOD - 1));
        p = atomicAdd(&cur[d.y >> BSH], 1);
        pairs[p] = ((unsigned)s.y << BSH) | (unsigned)(d.y & (BNOD - 1));
        p = atomicAdd(&cur[d.z >> BSH], 1);
        pairs[p] = ((unsigned)s.z << BSH) | (unsigned)(d.z & (BNOD - 1));
        p = atomicAdd(&cur[d.w >> BSH], 1);
        pairs[p] = ((unsigned)s.w << BSH) | (unsigned)(d.w & (BNOD - 1));
    }
}

// ---------------------------------------------------------------------------
// Per-bucket counting sort of pairs by src-window (src>>10, 1024 bins).
// One block per bucket; out-of-place into `sorted` (distinct region).
// Turns the layer gathers into loosely-lockstep sweeps of 64 KB windows.
// ---------------------------------------------------------------------------
__global__ __launch_bounds__(256) void k_srcsort(
    const int* __restrict__ scan, const unsigned int* __restrict__ pairs,
    unsigned int* __restrict__ sorted)
{
    __shared__ int hist[SBIN], h2[SBIN], cur[SBIN];
    int t = threadIdx.x, b = blockIdx.x;
    int p0 = scan[b * NPART];
    int p1 = (b == NBUCK - 1) ? (int)NE : scan[(b + 1) * NPART];
    for (int i = t; i < SBIN; i += 256) hist[i] = 0;
    __syncthreads();
    for (int p = p0 + t; p < p1; p += 256)
        atomicAdd(&hist[pairs[p] >> (BSH + 10)], 1);
    __syncthreads();
    // inclusive Hillis-Steele scan over SBIN, ping-pong hist<->h2
    int* sp = hist; int* dp = h2;
    for (int off = 1; off < SBIN; off <<= 1) {
        for (int i = t; i < SBIN; i += 256)
            dp[i] = sp[i] + ((i >= off) ? sp[i - off] : 0);
        __syncthreads();
        int* tmp = sp; sp = dp; dp = tmp;
    }
    for (int i = t; i < SBIN; i += 256)
        cur[i] = p0 + ((i > 0) ? sp[i - 1] : 0);
    __syncthreads();
    for (int p = p0 + t; p < p1; p += 256) {
        unsigned v = pairs[p];
        int pos = atomicAdd(&cur[v >> (BSH + 10)], 1);
        sorted[pos] = v;
    }
}

// copy sorted pairs back over the original array (tier A+ in-place variant)
__global__ __launch_bounds__(256) void k_copypairs(
    const uint4* __restrict__ src, uint4* __restrict__ dst)
{
    long long i = (long long)blockIdx.x * blockDim.x + threadIdx.x;
    if (i < NE / 4) dst[i] = src[i];
}

// ---------------------------------------------------------------------------
// x -> xp: pad rows to 32 B (8 floats) so every gather is one aligned sector
// ---------------------------------------------------------------------------
__global__ __launch_bounds__(256) void k_xpad(
    const float* __restrict__ x, float* __restrict__ xp)
{
    int i = blockIdx.x * blockDim.x + threadIdx.x;
    if (i >= NN) return;
    const float* xr = x + (long long)i * F;
    float2 a = *(const float2*)(xr + 0);
    float2 b = *(const float2*)(xr + 2);
    float2 c = *(const float2*)(xr + 4);
    float4* o = (float4*)(xp + ((long long)i << 3));
    o[0] = make_float4(a.x, a.y, b.x, b.y);
    o[1] = make_float4(c.x, c.y, 0.0f, 0.0f);
}

// ---------------------------------------------------------------------------
// Layer 1 (padded): gather xp (1 sector/edge), LDS fp64 accum,
// h1 -> padded 64 B double rows (h1p)
// ---------------------------------------------------------------------------
__global__ __launch_bounds__(256) void k_layer1p(
    const float* __restrict__ xp, const int* __restrict__ scan,
    const unsigned int* __restrict__ pairs,
    const float* __restrict__ Wrel, const float* __restrict__ Wroot,
    const float* __restrict__ bias, double* __restrict__ h1p)
{
    __shared__ double sAcc[BNOD * F];           // 48 KB
    __shared__ double sR[F * F], sT[F * F], sB[F];
    int t = threadIdx.x, b = blockIdx.x;
    if (t < F * F) { sR[t] = (double)Wrel[t]; sT[t] = (double)Wroot[t]; }
    if (t < F) sB[t] = (double)bias[t];
    for (int i = t; i < BNOD * F; i += 256) sAcc[i] = 0.0;
    __syncthreads();

    long long p0 = scan[b * NPART];
    long long p1 = (b == NBUCK - 1) ? NE : (long long)scan[(b + 1) * NPART];
    for (long long p = p0 + t; p < p1; p += 256) {
        unsigned v = pairs[p];
        const float4* xr = (const float4*)(xp + ((long long)(v >> BSH) << 3));
        float4 a = xr[0];
        float4 c = xr[1];
        double* ap = sAcc + (v & (BNOD - 1)) * F;
        unsafeAtomicAdd(ap + 0, (double)a.x);
        unsafeAtomicAdd(ap + 1, (double)a.y);
        unsafeAtomicAdd(ap + 2, (double)a.z);
        unsafeAtomicAdd(ap + 3, (double)a.w);
        unsafeAtomicAdd(ap + 4, (double)c.x);
        unsafeAtomicAdd(ap + 5, (double)c.y);
    }
    __syncthreads();

    int nodeBase = b << BSH;
    int numNodes = (NN - nodeBase < BNOD) ? (NN - nodeBase) : BNOD;
    for (int n = t; n < numNodes; n += 256) {
        long long i = nodeBase + n;
        const double* ac = sAcc + n * F;
        const float4* xr = (const float4*)(xp + (i << 3));
        float4 a = xr[0];
        float4 c = xr[1];
        double xv[F] = {(double)a.x, (double)a.y, (double)a.z,
                        (double)a.w, (double)c.x, (double)c.y};
        double hv[F];
        #pragma unroll
        for (int k = 0; k < F; ++k) {
            double h = sB[k];
            #pragma unroll
            for (int j = 0; j < F; ++j)
                h += ac[j] * sR[k * F + j] + xv[j] * sT[k * F + j];
            hv[k] = h;
        }
        double* hr = h1p + (i << 3);
        *(double2*)(hr + 0) = make_double2(hv[0], hv[1]);
        *(double2*)(hr + 2) = make_double2(hv[2], hv[3]);
        *(double2*)(hr + 4) = make_double2(hv[4], hv[5]);
    }
}

// ---------------------------------------------------------------------------
// Layer 2 (padded): gather h1p (1 sector/edge), LDS fp64 accum,
// argmax -> one-hot written directly to out
// ---------------------------------------------------------------------------
__global__ __launch_bounds__(256) void k_layer2p(
    const double* __restrict__ h1p, const int* __restrict__ scan,
    const unsigned int* __restrict__ pairs,
    const float* __restrict__ Wrel, const float* __restrict__ Wroot,
    const float* __restrict__ bias, float* __restrict__ out)
{
    __shared__ double sAcc[BNOD * F];
    __shared__ double sR[F * F], sT[F * F], sB[F];
    int t = threadIdx.x, b = blockIdx.x;
    if (t < F * F) { sR[t] = (double)Wrel[t]; sT[t] = (double)Wroot[t]; }
    if (t < F) sB[t] = (double)bias[t];
    for (int i = t; i < BNOD * F; i += 256) sAcc[i] = 0.0;
    __syncthreads();

    long long p0 = scan[b * NPART];
    long long p1 = (b == NBUCK - 1) ? NE : (long long)scan[(b + 1) * NPART];
    for (long long p = p0 + t; p < p1; p += 256) {
        unsigned v = pairs[p];
        const double* hr = h1p + ((long long)(v >> BSH) << 3);
        double2 d01 = *(const double2*)(hr + 0);
        double2 d23 = *(const double2*)(hr + 2);
        double2 d45 = *(const double2*)(hr + 4);
        double* ap = sAcc + (v & (BNOD - 1)) * F;
        unsafeAtomicAdd(ap + 0, d01.x);
        unsafeAtomicAdd(ap + 1, d01.y);
        unsafeAtomicAdd(ap + 2, d23.x);
        unsafeAtomicAdd(ap + 3, d23.y);
        unsafeAtomicAdd(ap + 4, d45.x);
        unsafeAtomicAdd(ap + 5, d45.y);
    }
    __syncthreads();

    int nodeBase = b << BSH;
    int numNodes = (NN - nodeBase < BNOD) ? (NN - nodeBase) : BNOD;
    for (int n = t; n < numNodes; n += 256) {
        long long i = nodeBase + n;
        const double* ac = sAcc + n * F;
        const double* hr = h1p + (i << 3);
        double h2[F];
        #pragma unroll
        for (int k = 0; k < F; ++k) {
            double h = sB[k];
            #pragma unroll
            for (int j = 0; j < F; ++j)
                h += ac[j] * sR[k * F + j] + hr[j] * sT[k * F + j];
            h2[k] = h;
        }
        int bi = 0;
        double bv = h2[0];
        #pragma unroll
        for (int k = 1; k < F; ++k)
            if (h2[k] > bv) { bv = h2[k]; bi = k; }
        float o[F];
        #pragma unroll
        for (int k = 0; k < F; ++k) o[k] = (k == bi) ? 1.0f : 0.0f;
        float2* op = (float2*)(out + i * F);
        op[0] = make_float2(o[0], o[1]);
        op[1] = make_float2(o[2], o[3]);
        op[2] = make_float2(o[4], o[5]);
    }
}

// ===================== tier B: round-4 proven path ==========================
__global__ __launch_bounds__(256) void k_layer1(
    const float* __restrict__ x, const int* __restrict__ scan,
    const unsigned int* __restrict__ pairs,
    const float* __restrict__ Wrel, const float* __restrict__ Wroot,
    const float* __restrict__ bias,
    float* __restrict__ h_hi, float* __restrict__ h_lo)
{
    __shared__ double sAcc[BNOD * F];
    __shared__ double sR[F * F], sT[F * F], sB[F];
    int t = threadIdx.x, b = blockIdx.x;
    if (t < F * F) { sR[t] = (double)Wrel[t]; sT[t] = (double)Wroot[t]; }
    if (t < F) sB[t] = (double)bias[t];
    for (int i = t; i < BNOD * F; i += 256) sAcc[i] = 0.0;
    __syncthreads();
    long long p0 = scan[b * NPART];
    long long p1 = (b == NBUCK - 1) ? NE : (long long)scan[(b + 1) * NPART];
    for (long long p = p0 + t; p < p1; p += 256) {
        unsigned v = pairs[p];
        const float* xr = x + (long long)(v >> BSH) * F;
        float2 a = *(const float2*)(xr + 0);
        float2 bb = *(const float2*)(xr + 2);
        float2 c = *(const float2*)(xr + 4);
        double* ap = sAcc + (v & (BNOD - 1)) * F;
        unsafeAtomicAdd(ap + 0, (double)a.x);
        unsafeAtomicAdd(ap + 1, (double)a.y);
        unsafeAtomicAdd(ap + 2, (double)bb.x);
        unsafeAtomicAdd(ap + 3, (double)bb.y);
        unsafeAtomicAdd(ap + 4, (double)c.x);
        unsafeAtomicAdd(ap + 5, (double)c.y);
    }
    __syncthreads();
    int nodeBase = b << BSH;
    int numNodes = (NN - nodeBase < BNOD) ? (NN - nodeBase) : BNOD;
    for (int n = t; n < numNodes; n += 256) {
        long long i = nodeBase + n;
        const double* ac = sAcc + n * F;
        const float* xi = x + i * F;
        double xv[F];
        #pragma unroll
        for (int j = 0; j < F; ++j) xv[j] = (double)xi[j];
        float* hh = h_hi + i * F;
        float* hl = h_lo + i * F;
        #pragma unroll
        for (int k = 0; k < F; ++k) {
            double h = sB[k];
            #pragma unroll
            for (int j = 0; j < F; ++j)
                h += ac[j] * sR[k * F + j] + xv[j] * sT[k * F + j];
            float hi = (float)h;
            hh[k] = hi;
            hl[k] = (float)(h - (double)hi);
        }
    }
}

__global__ __launch_bounds__(256) void k_layer2(
    const float* __restrict__ h_hi, const float* __restrict__ h_lo,
    const int* __restrict__ scan, const unsigned int* __restrict__ pairs,
    const float* __restrict__ Wrel, const float* __restrict__ Wroot,
    const float* __restrict__ bias, unsigned char* __restrict__ best)
{
    __shared__ double sAcc[BNOD * F];
    __shared__ double sR[F * F], sT[F * F], sB[F];
    int t = threadIdx.x, b = blockIdx.x;
    if (t < F * F) { sR[t] = (double)Wrel[t]; sT[t] = (double)Wroot[t]; }
    if (t < F) sB[t] = (double)bias[t];
    for (int i = t; i < BNOD * F; i += 256) sAcc[i] = 0.0;
    __syncthreads();
    long long p0 = scan[b * NPART];
    long long p1 = (b == NBUCK - 1) ? NE : (long long)scan[(b + 1) * NPART];
    for (long long p = p0 + t; p < p1; p += 256) {
        unsigned v = pairs[p];
        long long r = (long long)(v >> BSH) * F;
        int dl = (int)(v & (BNOD - 1));
        float2 a  = *(const float2*)(h_hi + r + 0);
        float2 bb = *(const float2*)(h_hi + r + 2);
        float2 c  = *(const float2*)(h_hi + r + 4);
        float2 la = *(const float2*)(h_lo + r + 0);
        float2 lb = *(const float2*)(h_lo + r + 2);
        float2 lc = *(const float2*)(h_lo + r + 4);
        double* ap = sAcc + dl * F;
        unsafeAtomicAdd(ap + 0, (double)a.x + (double)la.x);
        unsafeAtomicAdd(ap + 1, (double)a.y + (double)la.y);
        unsafeAtomicAdd(ap + 2, (double)bb.x + (double)lb.x);
        unsafeAtomicAdd(ap + 3, (double)bb.y + (double)lb.y);
        unsafeAtomicAdd(ap + 4, (double)c.x + (double)lc.x);
        unsafeAtomicAdd(ap + 5, (double)c.y + (double)lc.y);
    }
    __syncthreads();
    int nodeBase = b << BSH;
    int numNodes = (NN - nodeBase < BNOD) ? (NN - nodeBase) : BNOD;
    for (int n = t; n < numNodes; n += 256) {
        long long i = nodeBase + n;
        const double* ac = sAcc + n * F;
        long long ri = i * F;
        double hv[F];
        #pragma unroll
        for (int j = 0; j < F; ++j)
            hv[j] = (double)h_hi[ri + j] + (double)h_lo[ri + j];
        double h2[F];
        #pragma unroll
        for (int k = 0; k < F; ++k) {
            double h = sB[k];
            #pragma unroll
            for (int j = 0; j < F; ++j)
                h += ac[j] * sR[k * F + j] + hv[j] * sT[k * F + j];
            h2[k] = h;
        }
        int bi = 0;
        double bv = h2[0];
        #pragma unroll
        for (int k = 1; k < F; ++k)
            if (h2[k] > bv) { bv = h2[k]; bi = k; }
        best[i] = (unsigned char)bi;
    }
}

__global__ __launch_bounds__(256) void k_onehot(
    const unsigned char* __restrict__ best, float* __restrict__ out)
{
    int i = blockIdx.x * blockDim.x + threadIdx.x;
    if (i >= NN) return;
    int b = best[i];
    float* o = out + (long long)i * F;
    #pragma unroll
    for (int k = 0; k < F; ++k) o[k] = (k == b) ? 1.0f : 0.0f;
}

// ===================== tier C: atomic fallback ==============================
__global__ __launch_bounds__(256) void k_scatter_x(
    const float* __restrict__ x, const int* __restrict__ ei,
    double* __restrict__ agg)
{
    long long e = (long long)blockIdx.x * blockDim.x + threadIdx.x;
    if (e >= NE) return;
    int s = ei[e], d = ei[NE + e];
    const float* xr = x + (long long)s * F;
    double* ar = agg + (long long)d * F;
    float2 a = *(const float2*)(xr + 0);
    float2 b = *(const float2*)(xr + 2);
    float2 c = *(const float2*)(xr + 4);
    unsafeAtomicAdd(ar + 0, (double)a.x);
    unsafeAtomicAdd(ar + 1, (double)a.y);
    unsafeAtomicAdd(ar + 2, (double)b.x);
    unsafeAtomicAdd(ar + 3, (double)b.y);
    unsafeAtomicAdd(ar + 4, (double)c.x);
    unsafeAtomicAdd(ar + 5, (double)c.y);
}

__global__ __launch_bounds__(256) void k_lin1_f(
    const float* __restrict__ x, const double* __restrict__ agg,
    const float* __restrict__ Wrel, const float* __restrict__ Wroot,
    const float* __restrict__ bias, float* __restrict__ h)
{
    __shared__ double sR[F * F], sT[F * F], sB[F];
    int t = threadIdx.x;
    if (t < F * F) { sR[t] = (double)Wrel[t]; sT[t] = (double)Wroot[t]; }
    if (t < F) sB[t] = (double)bias[t];
    __syncthreads();
    long long i = (long long)blockIdx.x * blockDim.x + t;
    if (i >= NN) return;
    const float*  xr = x + i * F;
    const double* ar = agg + i * F;
    double xv[F], av[F];
    #pragma unroll
    for (int j = 0; j < F; ++j) { xv[j] = (double)xr[j]; av[j] = ar[j]; }
    float* hr = h + i * F;
    #pragma unroll
    for (int k = 0; k < F; ++k) {
        double a = sB[k];
        #pragma unroll
        for (int j = 0; j < F; ++j)
            a += av[j] * sR[k * F + j] + xv[j] * sT[k * F + j];
        hr[k] = (float)a;
    }
}

__global__ __launch_bounds__(256) void k_scatter_h32(
    const float* __restrict__ h, const int* __restrict__ ei,
    double* __restrict__ agg)
{
    long long e = (long long)blockIdx.x * blockDim.x + threadIdx.x;
    if (e >= NE) return;
    int s = ei[e], d = ei[NE + e];
    const float* hr = h + (long long)s * F;
    double* ar = agg + (long long)d * F;
    float2 a = *(const float2*)(hr + 0);
    float2 b = *(const float2*)(hr + 2);
    float2 c = *(const float2*)(hr + 4);
    unsafeAtomicAdd(ar + 0, (double)a.x);
    unsafeAtomicAdd(ar + 1, (double)a.y);
    unsafeAtomicAdd(ar + 2, (double)b.x);
    unsafeAtomicAdd(ar + 3, (double)b.y);
    unsafeAtomicAdd(ar + 4, (double)c.x);
    unsafeAtomicAdd(ar + 5, (double)c.y);
}

__global__ __launch_bounds__(256) void k_lin2_f(
    const float* __restrict__ h1, const double* __restrict__ agg,
    const float* __restrict__ Wrel, const float* __restrict__ Wroot,
    const float* __restrict__ bias, float* __restrict__ out)
{
    __shared__ double sR[F * F], sT[F * F], sB[F];
    int t = threadIdx.x;
    if (t < F * F) { sR[t] = (double)Wrel[t]; sT[t] = (double)Wroot[t]; }
    if (t < F) sB[t] = (double)bias[t];
    __syncthreads();
    long long i = (long long)blockIdx.x * blockDim.x + t;
    if (i >= NN) return;
    const float*  hr = h1 + i * F;
    const double* ar = agg + i * F;
    double hv[F], av[F];
    #pragma unroll
    for (int j = 0; j < F; ++j) { hv[j] = (double)hr[j]; av[j] = ar[j]; }
    double h2[F];
    #pragma unroll
    for (int k = 0; k < F; ++k) {
        double a = sB[k];
        #pragma unroll
        for (int j = 0; j < F; ++j)
            a += av[j] * sR[k * F + j] + hv[j] * sT[k * F + j];
        h2[k] = a;
    }
    int b = 0;
    double bv = h2[0];
    #pragma unroll
    for (int k = 1; k < F; ++k)
        if (h2[k] > bv) { bv = h2[k]; b = k; }
    float* o = out + i * F;
    #pragma unroll
    for (int k = 0; k < F; ++k) o[k] = (k == b) ? 1.0f : 0.0f;
}

// ============================================================================
extern "C" void kernel_launch(void* const* d_in, const int* in_sizes, int n_in,
                              void* d_out, int out_size, void* d_ws, size_t ws_size,
                              hipStream_t stream) {
    const float* x      = (const float*)d_in[0];
    const int*   ei     = (const int*)d_in[1];
    const float* Wrel1  = (const float*)d_in[2];
    const float* Wroot1 = (const float*)d_in[3];
    const float* b1     = (const float*)d_in[4];
    const float* Wrel2  = (const float*)d_in[5];
    const float* Wroot2 = (const float*)d_in[6];
    const float* b2     = (const float*)d_in[7];
    float* out = (float*)d_out;

    const int nb = (NN + 255) / 256;
    const int scanBlocks = (SCANN + SCAN_B - 1) / SCAN_B;   // 977
    const int cpBlocks = (int)((NE / 4 + 255) / 256);

    // ---- tier A layouts ---------------------------------------------------
    size_t o_pairs = 0;                                    // 64 MB
    size_t o_scan  = o_pairs + (size_t)NE * 4;             // ~1 MB
    size_t o_bsum  = o_scan + (size_t)SCANN * 4;
    size_t o_xp    = (o_bsum + 4096 + 63) & ~(size_t)63;   // 32 MB, 64B-aligned
    size_t o_h1p   = o_xp + (size_t)NN * 8 * 4;            // 64 MB, 64B-aligned
    size_t needA   = o_h1p + (size_t)NN * 8 * 8;           // ~161 MB
    size_t o_srt2  = needA;                                // 64 MB (A++ only)
    size_t needApp = o_srt2 + (size_t)NE * 4;              // ~225 MB

    // ---- tier B layout ----------------------------------------------------
    size_t b_hlo   = (o_bsum + 4096 + 15) & ~(size_t)15;
    size_t b_best  = b_hlo + (size_t)NN * F * 4;
    size_t needB   = b_best + (size_t)NN;                  // ~90 MB

    if (ws_size >= needA) {
        char* ws = (char*)d_ws;
        unsigned int* pairs = (unsigned int*)(ws + o_pairs);
        int*    scan = (int*)(ws + o_scan);
        int*    bsum = (int*)(ws + o_bsum);
        float*  xp   = (float*)(ws + o_xp);
        double* h1p  = (double*)(ws + o_h1p);
        bool big = (ws_size >= needApp);
        // A++: sort into dedicated region. A+: sort into (not-yet-used) h1p
        // region, then copy back over pairs. NE*4 == NN*8*8 bytes exactly.
        unsigned int* sorted = big ? (unsigned int*)(ws + o_srt2)
                                   : (unsigned int*)(ws + o_h1p);
        const unsigned int* lpairs = big ? sorted : pairs;

        k_bhist<<<NPART, 256, 0, stream>>>(ei, scan);
        k_xpad<<<nb, 256, 0, stream>>>(x, xp);
        k_scan_bsum<<<scanBlocks, SCAN_B, 0, stream>>>(scan, bsum, SCANN);
        k_scan_top<<<1, SCAN_B, 0, stream>>>(bsum, scanBlocks);
        k_scan_final<<<scanBlocks, SCAN_B, 0, stream>>>(scan, bsum, SCANN);
        k_partition<<<NPART, 256, 0, stream>>>(ei, scan, pairs);
        k_srcsort<<<NBUCK, 256, 0, stream>>>(scan, pairs, sorted);
        if (!big)
            k_copypairs<<<cpBlocks, 256, 0, stream>>>((const uint4*)sorted, (uint4*)pairs);
        k_layer1p<<<NBUCK, 256, 0, stream>>>(xp, scan, lpairs, Wrel1, Wroot1, b1, h1p);
        k_layer2p<<<NBUCK, 256, 0, stream>>>(h1p, scan, lpairs, Wrel2, Wroot2, b2, out);
    } else if (ws_size >= needB) {
        char* ws = (char*)d_ws;
        unsigned int* pairs = (unsigned int*)(ws + o_pairs);
        int*   scan  = (int*)(ws + o_scan);
        int*   bsum  = (int*)(ws + o_bsum);
        float* h_lo  = (float*)(ws + b_hlo);
        unsigned char* best = (unsigned char*)(ws + b_best);
        float* h_hi = out;

        k_bhist<<<NPART, 256, 0, stream>>>(ei, scan);
        k_scan_bsum<<<scanBlocks, SCAN_B, 0, stream>>>(scan, bsum, SCANN);
        k_scan_top<<<1, SCAN_B, 0, stream>>>(bsum, scanBlocks);
        k_scan_final<<<scanBlocks, SCAN_B, 0, stream>>>(scan, bsum, SCANN);
        k_partition<<<NPART, 256, 0, stream>>>(ei, scan, pairs);
        k_layer1<<<NBUCK, 256, 0, stream>>>(x, scan, pairs, Wrel1, Wroot1, b1, h_hi, h_lo);
        k_layer2<<<NBUCK, 256, 0, stream>>>(h_hi, h_lo, scan, pairs, Wrel2, Wroot2, b2, best);
        k_onehot<<<nb, 256, 0, stream>>>(best, out);
    } else {
        double* agg = (double*)d_ws;
        const size_t aggBytes = (size_t)NN * F * sizeof(double);
        const int eb = (int)((NE + 255) / 256);
        float* h1f = out;
        hipMemsetAsync(agg, 0, aggBytes, stream);
        k_scatter_x<<<eb, 256, 0, stream>>>(x, ei, agg);
        k_lin1_f<<<nb, 256, 0, stream>>>(x, agg, Wrel1, Wroot1, b1, h1f);
        hipMemsetAsync(agg, 0, aggBytes, stream);
        k_scatter_h32<<<eb, 256, 0, stream>>>(h1f, ei, agg);
        k_lin2_f<<<nb, 256, 0, stream>>>(h1f, agg, Wrel2, Wroot2, b2, out);
    }
}

// Round 7
// 857.267 us; speedup vs baseline: 10.0538x; 1.1911x over previous
//
#include <hip/hip_runtime.h>

static constexpr int       NN   = 1000000;
static constexpr long long NE   = 16000000;
static constexpr int       F    = 6;
static constexpr int       BSH  = 10;                 // 1024 nodes per bucket
static constexpr int       BNOD = 1 << BSH;
static constexpr int       NBUCK = (NN + BNOD - 1) / BNOD;   // 977
static constexpr int       NPART = 500;
static constexpr long long CHUNK = NE / NPART;        // 32000 exactly
static constexpr int       CH4   = (int)(CHUNK / 4);  // 8000 exactly
static constexpr int       SCANN = NBUCK * NPART;     // 488500
static constexpr int       SCAN_B = 256;
static constexpr int       SBIN  = 1024;              // src-sort bins (src>>10)

// ---------------------------------------------------------------------------
// Phase A: per-(bucket, partition-block) histogram (int4 edge loads)
// ---------------------------------------------------------------------------
__global__ __launch_bounds__(256) void k_bhist(
    const int* __restrict__ ei, int* __restrict__ bh)
{
    __shared__ int h[NBUCK];
    int t = threadIdx.x, blk = blockIdx.x;
    for (int i = t; i < NBUCK; i += 256) h[i] = 0;
    __syncthreads();
    const int4* d4 = (const int4*)(ei + NE + (long long)blk * CHUNK);
    for (int idx = t; idx < CH4; idx += 256) {
        int4 d = d4[idx];
        atomicAdd(&h[d.x >> BSH], 1);
        atomicAdd(&h[d.y >> BSH], 1);
        atomicAdd(&h[d.z >> BSH], 1);
        atomicAdd(&h[d.w >> BSH], 1);
    }
    __syncthreads();
    for (int i = t; i < NBUCK; i += 256) bh[i * NPART + blk] = h[i];
}

// ---------------------------------------------------------------------------
// Exclusive scan (two-level)
// ---------------------------------------------------------------------------
__global__ __launch_bounds__(SCAN_B) void k_scan_bsum(
    const int* __restrict__ a, int* __restrict__ bsum, int n)
{
    __shared__ int s[SCAN_B];
    int i = blockIdx.x * SCAN_B + threadIdx.x;
    s[threadIdx.x] = (i < n) ? a[i] : 0;
    __syncthreads();
    for (int off = SCAN_B / 2; off > 0; off >>= 1) {
        if (threadIdx.x < off) s[threadIdx.x] += s[threadIdx.x + off];
        __syncthreads();
    }
    if (threadIdx.x == 0) bsum[blockIdx.x] = s[0];
}

__global__ __launch_bounds__(SCAN_B) void k_scan_top(int* __restrict__ bsum, int n)
{
    __shared__ int s[SCAN_B];
    __shared__ int carry;
    if (threadIdx.x == 0) carry = 0;
    __syncthreads();
    for (int base = 0; base < n; base += SCAN_B) {
        int i = base + threadIdx.x;
        int v = (i < n) ? bsum[i] : 0;
        s[threadIdx.x] = v;
        __syncthreads();
        for (int off = 1; off < SCAN_B; off <<= 1) {
            int tv = (threadIdx.x >= off) ? s[threadIdx.x - off] : 0;
            __syncthreads();
            s[threadIdx.x] += tv;
            __syncthreads();
        }
        int incl = s[threadIdx.x];
        int total = s[SCAN_B - 1];
        if (i < n) bsum[i] = incl - v + carry;
        __syncthreads();
        if (threadIdx.x == 0) carry += total;
        __syncthreads();
    }
}

__global__ __launch_bounds__(SCAN_B) void k_scan_final(
    int* __restrict__ a, const int* __restrict__ bsum, int n)
{
    __shared__ int s[SCAN_B];
    int i = blockIdx.x * SCAN_B + threadIdx.x;
    int v = (i < n) ? a[i] : 0;
    s[threadIdx.x] = v;
    __syncthreads();
    for (int off = 1; off < SCAN_B; off <<= 1) {
        int tv = (threadIdx.x >= off) ? s[threadIdx.x - off] : 0;
        __syncthreads();
        s[threadIdx.x] += tv;
        __syncthreads();
    }
    if (i < n) a[i] = s[threadIdx.x] - v + bsum[blockIdx.x];
}

// ---------------------------------------------------------------------------
// Phase B: partition with LDS write-staging (8 entries = 32 B per flush).
// slot<8 -> staged; slot>=8 (rare burst) -> direct global at cur+slot (cur is
// stable intra-iteration). At each barrier: buckets with scnt>=8 flush their
// 8 staged words contiguously and advance cur by the full count.
// ---------------------------------------------------------------------------
__global__ __launch_bounds__(256) void k_partition(
    const int* __restrict__ ei, const int* __restrict__ scan,
    unsigned int* __restrict__ pairs)
{
    __shared__ int cur[NBUCK];
    __shared__ int scnt[NBUCK];
    __shared__ unsigned stg[NBUCK * 8];
    int t = threadIdx.x, blk = blockIdx.x;
    for (int i = t; i < NBUCK; i += 256) {
        cur[i] = scan[i * NPART + blk];
        scnt[i] = 0;
    }
    __syncthreads();
    const int4* s4 = (const int4*)(ei + (long long)blk * CHUNK);
    const int4* d4 = (const int4*)(ei + NE + (long long)blk * CHUNK);
    const int NITER = (CH4 + 255) / 256;
    for (int it = 0; it < NITER; ++it) {
        int idx = it * 256 + t;
        if (idx < CH4) {
            int4 s = s4[idx];
            int4 d = d4[idx];
            int ss[4] = {s.x, s.y, s.z, s.w};
            int dd[4] = {d.x, d.y, d.z, d.w};
            #pragma unroll
            for (int j = 0; j < 4; ++j) {
                int b = dd[j] >> BSH;
                unsigned v = ((unsigned)ss[j] << BSH) | (unsigned)(dd[j] & (BNOD - 1));
                int slot = atomicAdd(&scnt[b], 1);
                if (slot < 8) stg[b * 8 + slot] = v;
                else pairs[cur[b] + slot] = v;       // rare overflow
            }
        }
        __syncthreads();
        for (int b = t; b < NBUCK; b += 256) {
            int c = scnt[b];
            if (c >= 8) {
                int base = cur[b];
                #pragma unroll
                for (int i = 0; i < 8; ++i) pairs[base + i] = stg[b * 8 + i];
                cur[b] = base + c;                   // slots 8..c-1 went direct
                scnt[b] = 0;
            }
        }
        __syncthreads();
    }
    // drain remainders (<8 each)
    for (int b = t; b < NBUCK; b += 256) {
        int c = scnt[b];
        int base = cur[b];
        for (int i = 0; i < c; ++i) pairs[base + i] = stg[b * 8 + i];
    }
}

// ---------------------------------------------------------------------------
// Per-bucket counting sort of pairs by src-window (src>>10, 1024 bins).
// ---------------------------------------------------------------------------
__global__ __launch_bounds__(256) void k_srcsort(
    const int* __restrict__ scan, const unsigned int* __restrict__ pairs,
    unsigned int* __restrict__ sorted)
{
    __shared__ int hist[SBIN], h2[SBIN], cur[SBIN];
    int t = threadIdx.x, b = blockIdx.x;
    int p0 = scan[b * NPART];
    int p1 = (b == NBUCK - 1) ? (int)NE : scan[(b + 1) * NPART];
    for (int i = t; i < SBIN; i += 256) hist[i] = 0;
    __syncthreads();
    for (int p = p0 + t; p < p1; p += 256)
        atomicAdd(&hist[pairs[p] >> (BSH + 10)], 1);
    __syncthreads();
    int* sp = hist; int* dp = h2;
    for (int off = 1; off < SBIN; off <<= 1) {
        for (int i = t; i < SBIN; i += 256)
            dp[i] = sp[i] + ((i >= off) ? sp[i - off] : 0);
        __syncthreads();
        int* tmp = sp; sp = dp; dp = tmp;
    }
    for (int i = t; i < SBIN; i += 256)
        cur[i] = p0 + ((i > 0) ? sp[i - 1] : 0);
    __syncthreads();
    for (int p = p0 + t; p < p1; p += 256) {
        unsigned v = pairs[p];
        int pos = atomicAdd(&cur[v >> (BSH + 10)], 1);
        sorted[pos] = v;
    }
}

__global__ __launch_bounds__(256) void k_copypairs(
    const uint4* __restrict__ src, uint4* __restrict__ dst)
{
    long long i = (long long)blockIdx.x * blockDim.x + threadIdx.x;
    if (i < NE / 4) dst[i] = src[i];
}

// ---------------------------------------------------------------------------
// x -> xp: pad rows to 32 B (8 floats)
// ---------------------------------------------------------------------------
__global__ __launch_bounds__(256) void k_xpad(
    const float* __restrict__ x, float* __restrict__ xp)
{
    int i = blockIdx.x * blockDim.x + threadIdx.x;
    if (i >= NN) return;
    const float* xr = x + (long long)i * F;
    float2 a = *(const float2*)(xr + 0);
    float2 b = *(const float2*)(xr + 2);
    float2 c = *(const float2*)(xr + 4);
    float4* o = (float4*)(xp + ((long long)i << 3));
    o[0] = make_float4(a.x, a.y, b.x, b.y);
    o[1] = make_float4(c.x, c.y, 0.0f, 0.0f);
}

// ---------------------------------------------------------------------------
// Layer 1 (padded)
// ---------------------------------------------------------------------------
__global__ __launch_bounds__(256) void k_layer1p(
    const float* __restrict__ xp, const int* __restrict__ scan,
    const unsigned int* __restrict__ pairs,
    const float* __restrict__ Wrel, const float* __restrict__ Wroot,
    const float* __restrict__ bias, double* __restrict__ h1p)
{
    __shared__ double sAcc[BNOD * F];           // 48 KB
    __shared__ double sR[F * F], sT[F * F], sB[F];
    int t = threadIdx.x, b = blockIdx.x;
    if (t < F * F) { sR[t] = (double)Wrel[t]; sT[t] = (double)Wroot[t]; }
    if (t < F) sB[t] = (double)bias[t];
    for (int i = t; i < BNOD * F; i += 256) sAcc[i] = 0.0;
    __syncthreads();

    long long p0 = scan[b * NPART];
    long long p1 = (b == NBUCK - 1) ? NE : (long long)scan[(b + 1) * NPART];
    for (long long p = p0 + t; p < p1; p += 256) {
        unsigned v = pairs[p];
        const float4* xr = (const float4*)(xp + ((long long)(v >> BSH) << 3));
        float4 a = xr[0];
        float4 c = xr[1];
        double* ap = sAcc + (v & (BNOD - 1)) * F;
        unsafeAtomicAdd(ap + 0, (double)a.x);
        unsafeAtomicAdd(ap + 1, (double)a.y);
        unsafeAtomicAdd(ap + 2, (double)a.z);
        unsafeAtomicAdd(ap + 3, (double)a.w);
        unsafeAtomicAdd(ap + 4, (double)c.x);
        unsafeAtomicAdd(ap + 5, (double)c.y);
    }
    __syncthreads();

    int nodeBase = b << BSH;
    int numNodes = (NN - nodeBase < BNOD) ? (NN - nodeBase) : BNOD;
    for (int n = t; n < numNodes; n += 256) {
        long long i = nodeBase + n;
        const double* ac = sAcc + n * F;
        const float4* xr = (const float4*)(xp + (i << 3));
        float4 a = xr[0];
        float4 c = xr[1];
        double xv[F] = {(double)a.x, (double)a.y, (double)a.z,
                        (double)a.w, (double)c.x, (double)c.y};
        double hv[F];
        #pragma unroll
        for (int k = 0; k < F; ++k) {
            double h = sB[k];
            #pragma unroll
            for (int j = 0; j < F; ++j)
                h += ac[j] * sR[k * F + j] + xv[j] * sT[k * F + j];
            hv[k] = h;
        }
        double* hr = h1p + (i << 3);
        *(double2*)(hr + 0) = make_double2(hv[0], hv[1]);
        *(double2*)(hr + 2) = make_double2(hv[2], hv[3]);
        *(double2*)(hr + 4) = make_double2(hv[4], hv[5]);
    }
}

// ---------------------------------------------------------------------------
// Layer 2 (padded)
// ---------------------------------------------------------------------------
__global__ __launch_bounds__(256) void k_layer2p(
    const double* __restrict__ h1p, const int* __restrict__ scan,
    const unsigned int* __restrict__ pairs,
    const float* __restrict__ Wrel, const float* __restrict__ Wroot,
    const float* __restrict__ bias, float* __restrict__ out)
{
    __shared__ double sAcc[BNOD * F];
    __shared__ double sR[F * F], sT[F * F], sB[F];
    int t = threadIdx.x, b = blockIdx.x;
    if (t < F * F) { sR[t] = (double)Wrel[t]; sT[t] = (double)Wroot[t]; }
    if (t < F) sB[t] = (double)bias[t];
    for (int i = t; i < BNOD * F; i += 256) sAcc[i] = 0.0;
    __syncthreads();

    long long p0 = scan[b * NPART];
    long long p1 = (b == NBUCK - 1) ? NE : (long long)scan[(b + 1) * NPART];
    for (long long p = p0 + t; p < p1; p += 256) {
        unsigned v = pairs[p];
        const double* hr = h1p + ((long long)(v >> BSH) << 3);
        double2 d01 = *(const double2*)(hr + 0);
        double2 d23 = *(const double2*)(hr + 2);
        double2 d45 = *(const double2*)(hr + 4);
        double* ap = sAcc + (v & (BNOD - 1)) * F;
        unsafeAtomicAdd(ap + 0, d01.x);
        unsafeAtomicAdd(ap + 1, d01.y);
        unsafeAtomicAdd(ap + 2, d23.x);
        unsafeAtomicAdd(ap + 3, d23.y);
        unsafeAtomicAdd(ap + 4, d45.x);
        unsafeAtomicAdd(ap + 5, d45.y);
    }
    __syncthreads();

    int nodeBase = b << BSH;
    int numNodes = (NN - nodeBase < BNOD) ? (NN - nodeBase) : BNOD;
    for (int n = t; n < numNodes; n += 256) {
        long long i = nodeBase + n;
        const double* ac = sAcc + n * F;
        const double* hr = h1p + (i << 3);
        double h2[F];
        #pragma unroll
        for (int k = 0; k < F; ++k) {
            double h = sB[k];
            #pragma unroll
            for (int j = 0; j < F; ++j)
                h += ac[j] * sR[k * F + j] + hr[j] * sT[k * F + j];
            h2[k] = h;
        }
        int bi = 0;
        double bv = h2[0];
        #pragma unroll
        for (int k = 1; k < F; ++k)
            if (h2[k] > bv) { bv = h2[k]; bi = k; }
        float o[F];
        #pragma unroll
        for (int k = 0; k < F; ++k) o[k] = (k == bi) ? 1.0f : 0.0f;
        float2* op = (float2*)(out + i * F);
        op[0] = make_float2(o[0], o[1]);
        op[1] = make_float2(o[2], o[3]);
        op[2] = make_float2(o[4], o[5]);
    }
}

// ===================== tier B: hi/lo path ===================================
__global__ __launch_bounds__(256) void k_layer1(
    const float* __restrict__ x, const int* __restrict__ scan,
    const unsigned int* __restrict__ pairs,
    const float* __restrict__ Wrel, const float* __restrict__ Wroot,
    const float* __restrict__ bias,
    float* __restrict__ h_hi, float* __restrict__ h_lo)
{
    __shared__ double sAcc[BNOD * F];
    __shared__ double sR[F * F], sT[F * F], sB[F];
    int t = threadIdx.x, b = blockIdx.x;
    if (t < F * F) { sR[t] = (double)Wrel[t]; sT[t] = (double)Wroot[t]; }
    if (t < F) sB[t] = (double)bias[t];
    for (int i = t; i < BNOD * F; i += 256) sAcc[i] = 0.0;
    __syncthreads();
    long long p0 = scan[b * NPART];
    long long p1 = (b == NBUCK - 1) ? NE : (long long)scan[(b + 1) * NPART];
    for (long long p = p0 + t; p < p1; p += 256) {
        unsigned v = pairs[p];
        const float* xr = x + (long long)(v >> BSH) * F;
        float2 a = *(const float2*)(xr + 0);
        float2 bb = *(const float2*)(xr + 2);
        float2 c = *(const float2*)(xr + 4);
        double* ap = sAcc + (v & (BNOD - 1)) * F;
        unsafeAtomicAdd(ap + 0, (double)a.x);
        unsafeAtomicAdd(ap + 1, (double)a.y);
        unsafeAtomicAdd(ap + 2, (double)bb.x);
        unsafeAtomicAdd(ap + 3, (double)bb.y);
        unsafeAtomicAdd(ap + 4, (double)c.x);
        unsafeAtomicAdd(ap + 5, (double)c.y);
    }
    __syncthreads();
    int nodeBase = b << BSH;
    int numNodes = (NN - nodeBase < BNOD) ? (NN - nodeBase) : BNOD;
    for (int n = t; n < numNodes; n += 256) {
        long long i = nodeBase + n;
        const double* ac = sAcc + n * F;
        const float* xi = x + i * F;
        double xv[F];
        #pragma unroll
        for (int j = 0; j < F; ++j) xv[j] = (double)xi[j];
        float* hh = h_hi + i * F;
        float* hl = h_lo + i * F;
        #pragma unroll
        for (int k = 0; k < F; ++k) {
            double h = sB[k];
            #pragma unroll
            for (int j = 0; j < F; ++j)
                h += ac[j] * sR[k * F + j] + xv[j] * sT[k * F + j];
            float hi = (float)h;
            hh[k] = hi;
            hl[k] = (float)(h - (double)hi);
        }
    }
}

__global__ __launch_bounds__(256) void k_layer2(
    const float* __restrict__ h_hi, const float* __restrict__ h_lo,
    const int* __restrict__ scan, const unsigned int* __restrict__ pairs,
    const float* __restrict__ Wrel, const float* __restrict__ Wroot,
    const float* __restrict__ bias, unsigned char* __restrict__ best)
{
    __shared__ double sAcc[BNOD * F];
    __shared__ double sR[F * F], sT[F * F], sB[F];
    int t = threadIdx.x, b = blockIdx.x;
    if (t < F * F) { sR[t] = (double)Wrel[t]; sT[t] = (double)Wroot[t]; }
    if (t < F) sB[t] = (double)bias[t];
    for (int i = t; i < BNOD * F; i += 256) sAcc[i] = 0.0;
    __syncthreads();
    long long p0 = scan[b * NPART];
    long long p1 = (b == NBUCK - 1) ? NE : (long long)scan[(b + 1) * NPART];
    for (long long p = p0 + t; p < p1; p += 256) {
        unsigned v = pairs[p];
        long long r = (long long)(v >> BSH) * F;
        int dl = (int)(v & (BNOD - 1));
        float2 a  = *(const float2*)(h_hi + r + 0);
        float2 bb = *(const float2*)(h_hi + r + 2);
        float2 c  = *(const float2*)(h_hi + r + 4);
        float2 la = *(const float2*)(h_lo + r + 0);
        float2 lb = *(const float2*)(h_lo + r + 2);
        float2 lc = *(const float2*)(h_lo + r + 4);
        double* ap = sAcc + dl * F;
        unsafeAtomicAdd(ap + 0, (double)a.x + (double)la.x);
        unsafeAtomicAdd(ap + 1, (double)a.y + (double)la.y);
        unsafeAtomicAdd(ap + 2, (double)bb.x + (double)lb.x);
        unsafeAtomicAdd(ap + 3, (double)bb.y + (double)lb.y);
        unsafeAtomicAdd(ap + 4, (double)c.x + (double)lc.x);
        unsafeAtomicAdd(ap + 5, (double)c.y + (double)lc.y);
    }
    __syncthreads();
    int nodeBase = b << BSH;
    int numNodes = (NN - nodeBase < BNOD) ? (NN - nodeBase) : BNOD;
    for (int n = t; n < numNodes; n += 256) {
        long long i = nodeBase + n;
        const double* ac = sAcc + n * F;
        long long ri = i * F;
        double hv[F];
        #pragma unroll
        for (int j = 0; j < F; ++j)
            hv[j] = (double)h_hi[ri + j] + (double)h_lo[ri + j];
        double h2[F];
        #pragma unroll
        for (int k = 0; k < F; ++k) {
            double h = sB[k];
            #pragma unroll
            for (int j = 0; j < F; ++j)
                h += ac[j] * sR[k * F + j] + hv[j] * sT[k * F + j];
            h2[k] = h;
        }
        int bi = 0;
        double bv = h2[0];
        #pragma unroll
        for (int k = 1; k < F; ++k)
            if (h2[k] > bv) { bv = h2[k]; bi = k; }
        best[i] = (unsigned char)bi;
    }
}

__global__ __launch_bounds__(256) void k_onehot(
    const unsigned char* __restrict__ best, float* __restrict__ out)
{
    int i = blockIdx.x * blockDim.x + threadIdx.x;
    if (i >= NN) return;
    int b = best[i];
    float* o = out + (long long)i * F;
    #pragma unroll
    for (int k = 0; k < F; ++k) o[k] = (k == b) ? 1.0f : 0.0f;
}

// ===================== tier C: atomic fallback ==============================
__global__ __launch_bounds__(256) void k_scatter_x(
    const float* __restrict__ x, const int* __restrict__ ei,
    double* __restrict__ agg)
{
    long long e = (long long)blockIdx.x * blockDim.x + threadIdx.x;
    if (e >= NE) return;
    int s = ei[e], d = ei[NE + e];
    const float* xr = x + (long long)s * F;
    double* ar = agg + (long long)d * F;
    float2 a = *(const float2*)(xr + 0);
    float2 b = *(const float2*)(xr + 2);
    float2 c = *(const float2*)(xr + 4);
    unsafeAtomicAdd(ar + 0, (double)a.x);
    unsafeAtomicAdd(ar + 1, (double)a.y);
    unsafeAtomicAdd(ar + 2, (double)b.x);
    unsafeAtomicAdd(ar + 3, (double)b.y);
    unsafeAtomicAdd(ar + 4, (double)c.x);
    unsafeAtomicAdd(ar + 5, (double)c.y);
}

__global__ __launch_bounds__(256) void k_lin1_f(
    const float* __restrict__ x, const double* __restrict__ agg,
    const float* __restrict__ Wrel, const float* __restrict__ Wroot,
    const float* __restrict__ bias, float* __restrict__ h)
{
    __shared__ double sR[F * F], sT[F * F], sB[F];
    int t = threadIdx.x;
    if (t < F * F) { sR[t] = (double)Wrel[t]; sT[t] = (double)Wroot[t]; }
    if (t < F) sB[t] = (double)bias[t];
    __syncthreads();
    long long i = (long long)blockIdx.x * blockDim.x + t;
    if (i >= NN) return;
    const float*  xr = x + i * F;
    const double* ar = agg + i * F;
    double xv[F], av[F];
    #pragma unroll
    for (int j = 0; j < F; ++j) { xv[j] = (double)xr[j]; av[j] = ar[j]; }
    float* hr = h + i * F;
    #pragma unroll
    for (int k = 0; k < F; ++k) {
        double a = sB[k];
        #pragma unroll
        for (int j = 0; j < F; ++j)
            a += av[j] * sR[k * F + j] + xv[j] * sT[k * F + j];
        hr[k] = (float)a;
    }
}

__global__ __launch_bounds__(256) void k_scatter_h32(
    const float* __restrict__ h, const int* __restrict__ ei,
    double* __restrict__ agg)
{
    long long e = (long long)blockIdx.x * blockDim.x + threadIdx.x;
    if (e >= NE) return;
    int s = ei[e], d = ei[NE + e];
    const float* hr = h + (long long)s * F;
    double* ar = agg + (long long)d * F;
    float2 a = *(const float2*)(hr + 0);
    float2 b = *(const float2*)(hr + 2);
    float2 c = *(const float2*)(hr + 4);
    unsafeAtomicAdd(ar + 0, (double)a.x);
    unsafeAtomicAdd(ar + 1, (double)a.y);
    unsafeAtomicAdd(ar + 2, (double)b.x);
    unsafeAtomicAdd(ar + 3, (double)b.y);
    unsafeAtomicAdd(ar + 4, (double)c.x);
    unsafeAtomicAdd(ar + 5, (double)c.y);
}

__global__ __launch_bounds__(256) void k_lin2_f(
    const float* __restrict__ h1, const double* __restrict__ agg,
    const float* __restrict__ Wrel, const float* __restrict__ Wroot,
    const float* __restrict__ bias, float* __restrict__ out)
{
    __shared__ double sR[F * F], sT[F * F], sB[F];
    int t = threadIdx.x;
    if (t < F * F) { sR[t] = (double)Wrel[t]; sT[t] = (double)Wroot[t]; }
    if (t < F) sB[t] = (double)bias[t];
    __syncthreads();
    long long i = (long long)blockIdx.x * blockDim.x + t;
    if (i >= NN) return;
    const float*  hr = h1 + i * F;
    const double* ar = agg + i * F;
    double hv[F], av[F];
    #pragma unroll
    for (int j = 0; j < F; ++j) { hv[j] = (double)hr[j]; av[j] = ar[j]; }
    double h2[F];
    #pragma unroll
    for (int k = 0; k < F; ++k) {
        double a = sB[k];
        #pragma unroll
        for (int j = 0; j < F; ++j)
            a += av[j] * sR[k * F + j] + hv[j] * sT[k * F + j];
        h2[k] = a;
    }
    int b = 0;
    double bv = h2[0];
    #pragma unroll
    for (int k = 1; k < F; ++k)
        if (h2[k] > bv) { bv = h2[k]; b = k; }
    float* o = out + i * F;
    #pragma unroll
    for (int k = 0; k < F; ++k) o[k] = (k == b) ? 1.0f : 0.0f;
}

// ============================================================================
extern "C" void kernel_launch(void* const* d_in, const int* in_sizes, int n_in,
                              void* d_out, int out_size, void* d_ws, size_t ws_size,
                              hipStream_t stream) {
    const float* x      = (const float*)d_in[0];
    const int*   ei     = (const int*)d_in[1];
    const float* Wrel1  = (const float*)d_in[2];
    const float* Wroot1 = (const float*)d_in[3];
    const float* b1     = (const float*)d_in[4];
    const float* Wrel2  = (const float*)d_in[5];
    const float* Wroot2 = (const float*)d_in[6];
    const float* b2     = (const float*)d_in[7];
    float* out = (float*)d_out;

    const int nb = (NN + 255) / 256;
    const int scanBlocks = (SCANN + SCAN_B - 1) / SCAN_B;   // 1909
    const int cpBlocks = (int)((NE / 4 + 255) / 256);

    // ---- tier A layouts ---------------------------------------------------
    size_t o_pairs = 0;                                    // 64 MB
    size_t o_scan  = o_pairs + (size_t)NE * 4;             // ~1.9 MB
    size_t o_bsum  = o_scan + (size_t)SCANN * 4;
    size_t o_xp    = (o_bsum + 16384 + 63) & ~(size_t)63;  // 32 MB, 64B-aligned
    size_t o_h1p   = o_xp + (size_t)NN * 8 * 4;            // 64 MB, 64B-aligned
    size_t needA   = o_h1p + (size_t)NN * 8 * 8;           // ~162 MB
    size_t o_srt2  = needA;                                // 64 MB (A++ only)
    size_t needApp = o_srt2 + (size_t)NE * 4;              // ~226 MB

    // ---- tier B layout ----------------------------------------------------
    size_t b_hlo   = (o_bsum + 16384 + 15) & ~(size_t)15;
    size_t b_best  = b_hlo + (size_t)NN * F * 4;
    size_t needB   = b_best + (size_t)NN;                  // ~91 MB

    if (ws_size >= needA) {
        char* ws = (char*)d_ws;
        unsigned int* pairs = (unsigned int*)(ws + o_pairs);
        int*    scan = (int*)(ws + o_scan);
        int*    bsum = (int*)(ws + o_bsum);
        float*  xp   = (float*)(ws + o_xp);
        double* h1p  = (double*)(ws + o_h1p);
        bool big = (ws_size >= needApp);
        unsigned int* sorted = big ? (unsigned int*)(ws + o_srt2)
                                   : (unsigned int*)(ws + o_h1p);
        const unsigned int* lpairs = big ? sorted : pairs;

        k_bhist<<<NPART, 256, 0, stream>>>(ei, scan);
        k_xpad<<<nb, 256, 0, stream>>>(x, xp);
        k_scan_bsum<<<scanBlocks, SCAN_B, 0, stream>>>(scan, bsum, SCANN);
        k_scan_top<<<1, SCAN_B, 0, stream>>>(bsum, scanBlocks);
        k_scan_final<<<scanBlocks, SCAN_B, 0, stream>>>(scan, bsum, SCANN);
        k_partition<<<NPART, 256, 0, stream>>>(ei, scan, pairs);
        k_srcsort<<<NBUCK, 256, 0, stream>>>(scan, pairs, sorted);
        if (!big)
            k_copypairs<<<cpBlocks, 256, 0, stream>>>((const uint4*)sorted, (uint4*)pairs);
        k_layer1p<<<NBUCK, 256, 0, stream>>>(xp, scan, lpairs, Wrel1, Wroot1, b1, h1p);
        k_layer2p<<<NBUCK, 256, 0, stream>>>(h1p, scan, lpairs, Wrel2, Wroot2, b2, out);
    } else if (ws_size >= needB) {
        char* ws = (char*)d_ws;
        unsigned int* pairs = (unsigned int*)(ws + o_pairs);
        int*   scan  = (int*)(ws + o_scan);
        int*   bsum  = (int*)(ws + o_bsum);
        float* h_lo  = (float*)(ws + b_hlo);
        unsigned char* best = (unsigned char*)(ws + b_best);
        float* h_hi = out;

        k_bhist<<<NPART, 256, 0, stream>>>(ei, scan);
        k_scan_bsum<<<scanBlocks, SCAN_B, 0, stream>>>(scan, bsum, SCANN);
        k_scan_top<<<1, SCAN_B, 0, stream>>>(bsum, scanBlocks);
        k_scan_final<<<scanBlocks, SCAN_B, 0, stream>>>(scan, bsum, SCANN);
        k_partition<<<NPART, 256, 0, stream>>>(ei, scan, pairs);
        k_layer1<<<NBUCK, 256, 0, stream>>>(x, scan, pairs, Wrel1, Wroot1, b1, h_hi, h_lo);
        k_layer2<<<NBUCK, 256, 0, stream>>>(h_hi, h_lo, scan, pairs, Wrel2, Wroot2, b2, best);
        k_onehot<<<nb, 256, 0, stream>>>(best, out);
    } else {
        double* agg = (double*)d_ws;
        const size_t aggBytes = (size_t)NN * F * sizeof(double);
        const int eb = (int)((NE + 255) / 256);
        float* h1f = out;
        hipMemsetAsync(agg, 0, aggBytes, stream);
        k_scatter_x<<<eb, 256, 0, stream>>>(x, ei, agg);
        k_lin1_f<<<nb, 256, 0, stream>>>(x, agg, Wrel1, Wroot1, b1, h1f);
        hipMemsetAsync(agg, 0, aggBytes, stream);
        k_scatter_h32<<<eb, 256, 0, stream>>>(h1f, ei, agg);
        k_lin2_f<<<nb, 256, 0, stream>>>(h1f, agg, Wrel2, Wroot2, b2, out);
    }
}

// Round 8
// 805.369 us; speedup vs baseline: 10.7017x; 1.0644x over previous
//
#include <hip/hip_runtime.h>

static constexpr int       NN   = 1000000;
static constexpr long long NE   = 16000000;
static constexpr int       F    = 6;
static constexpr int       BSH  = 10;                 // 1024 nodes per bucket
static constexpr int       BNOD = 1 << BSH;
static constexpr int       NBUCK = (NN + BNOD - 1) / BNOD;   // 977
static constexpr int       NPART = 500;
static constexpr long long CHUNK = NE / NPART;        // 32000 exactly
static constexpr int       CH4   = (int)(CHUNK / 4);  // 8000 exactly
static constexpr int       SCANN = NBUCK * NPART;     // 488500
static constexpr int       SCAN_B = 256;
static constexpr int       SBIN  = 1024;              // src-sort bins (src>>10)

// ---------------------------------------------------------------------------
// Phase A: per-(bucket, partition-block) histogram (int4 edge loads)
// ---------------------------------------------------------------------------
__global__ __launch_bounds__(256) void k_bhist(
    const int* __restrict__ ei, int* __restrict__ bh)
{
    __shared__ int h[NBUCK];
    int t = threadIdx.x, blk = blockIdx.x;
    for (int i = t; i < NBUCK; i += 256) h[i] = 0;
    __syncthreads();
    const int4* d4 = (const int4*)(ei + NE + (long long)blk * CHUNK);
    for (int idx = t; idx < CH4; idx += 256) {
        int4 d = d4[idx];
        atomicAdd(&h[d.x >> BSH], 1);
        atomicAdd(&h[d.y >> BSH], 1);
        atomicAdd(&h[d.z >> BSH], 1);
        atomicAdd(&h[d.w >> BSH], 1);
    }
    __syncthreads();
    for (int i = t; i < NBUCK; i += 256) bh[i * NPART + blk] = h[i];
}

// ---------------------------------------------------------------------------
// Exclusive scan (two-level)
// ---------------------------------------------------------------------------
__global__ __launch_bounds__(SCAN_B) void k_scan_bsum(
    const int* __restrict__ a, int* __restrict__ bsum, int n)
{
    __shared__ int s[SCAN_B];
    int i = blockIdx.x * SCAN_B + threadIdx.x;
    s[threadIdx.x] = (i < n) ? a[i] : 0;
    __syncthreads();
    for (int off = SCAN_B / 2; off > 0; off >>= 1) {
        if (threadIdx.x < off) s[threadIdx.x] += s[threadIdx.x + off];
        __syncthreads();
    }
    if (threadIdx.x == 0) bsum[blockIdx.x] = s[0];
}

__global__ __launch_bounds__(SCAN_B) void k_scan_top(int* __restrict__ bsum, int n)
{
    __shared__ int s[SCAN_B];
    __shared__ int carry;
    if (threadIdx.x == 0) carry = 0;
    __syncthreads();
    for (int base = 0; base < n; base += SCAN_B) {
        int i = base + threadIdx.x;
        int v = (i < n) ? bsum[i] : 0;
        s[threadIdx.x] = v;
        __syncthreads();
        for (int off = 1; off < SCAN_B; off <<= 1) {
            int tv = (threadIdx.x >= off) ? s[threadIdx.x - off] : 0;
            __syncthreads();
            s[threadIdx.x] += tv;
            __syncthreads();
        }
        int incl = s[threadIdx.x];
        int total = s[SCAN_B - 1];
        if (i < n) bsum[i] = incl - v + carry;
        __syncthreads();
        if (threadIdx.x == 0) carry += total;
        __syncthreads();
    }
}

__global__ __launch_bounds__(SCAN_B) void k_scan_final(
    int* __restrict__ a, const int* __restrict__ bsum, int n)
{
    __shared__ int s[SCAN_B];
    int i = blockIdx.x * SCAN_B + threadIdx.x;
    int v = (i < n) ? a[i] : 0;
    s[threadIdx.x] = v;
    __syncthreads();
    for (int off = 1; off < SCAN_B; off <<= 1) {
        int tv = (threadIdx.x >= off) ? s[threadIdx.x - off] : 0;
        __syncthreads();
        s[threadIdx.x] += tv;
        __syncthreads();
    }
    if (i < n) a[i] = s[threadIdx.x] - v + bsum[blockIdx.x];
}

// ---------------------------------------------------------------------------
// Phase B: partition with LDS write-staging (8 entries = 32 B per flush)
// ---------------------------------------------------------------------------
__global__ __launch_bounds__(256) void k_partition(
    const int* __restrict__ ei, const int* __restrict__ scan,
    unsigned int* __restrict__ pairs)
{
    __shared__ int cur[NBUCK];
    __shared__ int scnt[NBUCK];
    __shared__ unsigned stg[NBUCK * 8];
    int t = threadIdx.x, blk = blockIdx.x;
    for (int i = t; i < NBUCK; i += 256) {
        cur[i] = scan[i * NPART + blk];
        scnt[i] = 0;
    }
    __syncthreads();
    const int4* s4 = (const int4*)(ei + (long long)blk * CHUNK);
    const int4* d4 = (const int4*)(ei + NE + (long long)blk * CHUNK);
    const int NITER = (CH4 + 255) / 256;
    for (int it = 0; it < NITER; ++it) {
        int idx = it * 256 + t;
        if (idx < CH4) {
            int4 s = s4[idx];
            int4 d = d4[idx];
            int ss[4] = {s.x, s.y, s.z, s.w};
            int dd[4] = {d.x, d.y, d.z, d.w};
            #pragma unroll
            for (int j = 0; j < 4; ++j) {
                int b = dd[j] >> BSH;
                unsigned v = ((unsigned)ss[j] << BSH) | (unsigned)(dd[j] & (BNOD - 1));
                int slot = atomicAdd(&scnt[b], 1);
                if (slot < 8) stg[b * 8 + slot] = v;
                else pairs[cur[b] + slot] = v;       // rare overflow
            }
        }
        __syncthreads();
        for (int b = t; b < NBUCK; b += 256) {
            int c = scnt[b];
            if (c >= 8) {
                int base = cur[b];
                #pragma unroll
                for (int i = 0; i < 8; ++i) pairs[base + i] = stg[b * 8 + i];
                cur[b] = base + c;                   // slots 8..c-1 went direct
                scnt[b] = 0;
            }
        }
        __syncthreads();
    }
    for (int b = t; b < NBUCK; b += 256) {
        int c = scnt[b];
        int base = cur[b];
        for (int i = 0; i < c; ++i) pairs[base + i] = stg[b * 8 + i];
    }
}

// ---------------------------------------------------------------------------
// Per-bucket counting sort by src-window (src>>10, 1024 bins), now with the
// same LDS write-staging protocol (flush 32 B chunks at iteration barriers).
// ---------------------------------------------------------------------------
__global__ __launch_bounds__(256) void k_srcsort(
    const int* __restrict__ scan, const unsigned int* __restrict__ pairs,
    unsigned int* __restrict__ sorted)
{
    __shared__ int hist[SBIN], h2[SBIN], cur[SBIN], scnt[SBIN];
    __shared__ unsigned stg[SBIN * 8];               // 32 KB
    int t = threadIdx.x, b = blockIdx.x;
    int p0 = scan[b * NPART];
    int p1 = (b == NBUCK - 1) ? (int)NE : scan[(b + 1) * NPART];
    for (int i = t; i < SBIN; i += 256) hist[i] = 0;
    __syncthreads();
    for (int p = p0 + t; p < p1; p += 256)
        atomicAdd(&hist[pairs[p] >> (BSH + 10)], 1);
    __syncthreads();
    // inclusive Hillis-Steele scan, ping-pong hist<->h2
    int* sp = hist; int* dp = h2;
    for (int off = 1; off < SBIN; off <<= 1) {
        for (int i = t; i < SBIN; i += 256)
            dp[i] = sp[i] + ((i >= off) ? sp[i - off] : 0);
        __syncthreads();
        int* tmp = sp; sp = dp; dp = tmp;
    }
    for (int i = t; i < SBIN; i += 256) {
        cur[i] = p0 + ((i > 0) ? sp[i - 1] : 0);
        scnt[i] = 0;
    }
    __syncthreads();
    const int n = p1 - p0;
    const int NIT = (n + 255) / 256;
    for (int it = 0; it < NIT; ++it) {
        int p = p0 + it * 256 + t;
        if (p < p1) {
            unsigned v = pairs[p];
            int bin = (int)(v >> (BSH + 10));
            int slot = atomicAdd(&scnt[bin], 1);
            if (slot < 8) stg[bin * 8 + slot] = v;
            else sorted[cur[bin] + slot] = v;        // rare burst overflow
        }
        __syncthreads();
        for (int i = t; i < SBIN; i += 256) {
            int c = scnt[i];
            if (c >= 8) {
                int base = cur[i];
                #pragma unroll
                for (int j = 0; j < 8; ++j) sorted[base + j] = stg[i * 8 + j];
                cur[i] = base + c;
                scnt[i] = 0;
            }
        }
        __syncthreads();
    }
    for (int i = t; i < SBIN; i += 256) {
        int c = scnt[i];
        int base = cur[i];
        for (int j = 0; j < c; ++j) sorted[base + j] = stg[i * 8 + j];
    }
}

__global__ __launch_bounds__(256) void k_copypairs(
    const uint4* __restrict__ src, uint4* __restrict__ dst)
{
    long long i = (long long)blockIdx.x * blockDim.x + threadIdx.x;
    if (i < NE / 4) dst[i] = src[i];
}

// ---------------------------------------------------------------------------
// x -> xp: pad rows to 32 B (8 floats)
// ---------------------------------------------------------------------------
__global__ __launch_bounds__(256) void k_xpad(
    const float* __restrict__ x, float* __restrict__ xp)
{
    int i = blockIdx.x * blockDim.x + threadIdx.x;
    if (i >= NN) return;
    const float* xr = x + (long long)i * F;
    float2 a = *(const float2*)(xr + 0);
    float2 b = *(const float2*)(xr + 2);
    float2 c = *(const float2*)(xr + 4);
    float4* o = (float4*)(xp + ((long long)i << 3));
    o[0] = make_float4(a.x, a.y, b.x, b.y);
    o[1] = make_float4(c.x, c.y, 0.0f, 0.0f);
}

// ---------------------------------------------------------------------------
// Layer 1 (padded)
// ---------------------------------------------------------------------------
__global__ __launch_bounds__(256) void k_layer1p(
    const float* __restrict__ xp, const int* __restrict__ scan,
    const unsigned int* __restrict__ pairs,
    const float* __restrict__ Wrel, const float* __restrict__ Wroot,
    const float* __restrict__ bias, double* __restrict__ h1p)
{
    __shared__ double sAcc[BNOD * F];           // 48 KB
    __shared__ double sR[F * F], sT[F * F], sB[F];
    int t = threadIdx.x, b = blockIdx.x;
    if (t < F * F) { sR[t] = (double)Wrel[t]; sT[t] = (double)Wroot[t]; }
    if (t < F) sB[t] = (double)bias[t];
    for (int i = t; i < BNOD * F; i += 256) sAcc[i] = 0.0;
    __syncthreads();

    long long p0 = scan[b * NPART];
    long long p1 = (b == NBUCK - 1) ? NE : (long long)scan[(b + 1) * NPART];
    for (long long p = p0 + t; p < p1; p += 256) {
        unsigned v = pairs[p];
        const float4* xr = (const float4*)(xp + ((long long)(v >> BSH) << 3));
        float4 a = xr[0];
        float4 c = xr[1];
        double* ap = sAcc + (v & (BNOD - 1)) * F;
        unsafeAtomicAdd(ap + 0, (double)a.x);
        unsafeAtomicAdd(ap + 1, (double)a.y);
        unsafeAtomicAdd(ap + 2, (double)a.z);
        unsafeAtomicAdd(ap + 3, (double)a.w);
        unsafeAtomicAdd(ap + 4, (double)c.x);
        unsafeAtomicAdd(ap + 5, (double)c.y);
    }
    __syncthreads();

    int nodeBase = b << BSH;
    int numNodes = (NN - nodeBase < BNOD) ? (NN - nodeBase) : BNOD;
    for (int n = t; n < numNodes; n += 256) {
        long long i = nodeBase + n;
        const double* ac = sAcc + n * F;
        const float4* xr = (const float4*)(xp + (i << 3));
        float4 a = xr[0];
        float4 c = xr[1];
        double xv[F] = {(double)a.x, (double)a.y, (double)a.z,
                        (double)a.w, (double)c.x, (double)c.y};
        double hv[F];
        #pragma unroll
        for (int k = 0; k < F; ++k) {
            double h = sB[k];
            #pragma unroll
            for (int j = 0; j < F; ++j)
                h += ac[j] * sR[k * F + j] + xv[j] * sT[k * F + j];
            hv[k] = h;
        }
        double* hr = h1p + (i << 3);
        *(double2*)(hr + 0) = make_double2(hv[0], hv[1]);
        *(double2*)(hr + 2) = make_double2(hv[2], hv[3]);
        *(double2*)(hr + 4) = make_double2(hv[4], hv[5]);
    }
}

// ---------------------------------------------------------------------------
// Layer 2 (padded)
// ---------------------------------------------------------------------------
__global__ __launch_bounds__(256) void k_layer2p(
    const double* __restrict__ h1p, const int* __restrict__ scan,
    const unsigned int* __restrict__ pairs,
    const float* __restrict__ Wrel, const float* __restrict__ Wroot,
    const float* __restrict__ bias, float* __restrict__ out)
{
    __shared__ double sAcc[BNOD * F];
    __shared__ double sR[F * F], sT[F * F], sB[F];
    int t = threadIdx.x, b = blockIdx.x;
    if (t < F * F) { sR[t] = (double)Wrel[t]; sT[t] = (double)Wroot[t]; }
    if (t < F) sB[t] = (double)bias[t];
    for (int i = t; i < BNOD * F; i += 256) sAcc[i] = 0.0;
    __syncthreads();

    long long p0 = scan[b * NPART];
    long long p1 = (b == NBUCK - 1) ? NE : (long long)scan[(b + 1) * NPART];
    for (long long p = p0 + t; p < p1; p += 256) {
        unsigned v = pairs[p];
        const double* hr = h1p + ((long long)(v >> BSH) << 3);
        double2 d01 = *(const double2*)(hr + 0);
        double2 d23 = *(const double2*)(hr + 2);
        double2 d45 = *(const double2*)(hr + 4);
        double* ap = sAcc + (v & (BNOD - 1)) * F;
        unsafeAtomicAdd(ap + 0, d01.x);
        unsafeAtomicAdd(ap + 1, d01.y);
        unsafeAtomicAdd(ap + 2, d23.x);
        unsafeAtomicAdd(ap + 3, d23.y);
        unsafeAtomicAdd(ap + 4, d45.x);
        unsafeAtomicAdd(ap + 5, d45.y);
    }
    __syncthreads();

    int nodeBase = b << BSH;
    int numNodes = (NN - nodeBase < BNOD) ? (NN - nodeBase) : BNOD;
    for (int n = t; n < numNodes; n += 256) {
        long long i = nodeBase + n;
        const double* ac = sAcc + n * F;
        const double* hr = h1p + (i << 3);
        double h2[F];
        #pragma unroll
        for (int k = 0; k < F; ++k) {
            double h = sB[k];
            #pragma unroll
            for (int j = 0; j < F; ++j)
                h += ac[j] * sR[k * F + j] + hr[j] * sT[k * F + j];
            h2[k] = h;
        }
        int bi = 0;
        double bv = h2[0];
        #pragma unroll
        for (int k = 1; k < F; ++k)
            if (h2[k] > bv) { bv = h2[k]; bi = k; }
        float o[F];
        #pragma unroll
        for (int k = 0; k < F; ++k) o[k] = (k == bi) ? 1.0f : 0.0f;
        float2* op = (float2*)(out + i * F);
        op[0] = make_float2(o[0], o[1]);
        op[1] = make_float2(o[2], o[3]);
        op[2] = make_float2(o[4], o[5]);
    }
}

// ===================== tier B: hi/lo path ===================================
__global__ __launch_bounds__(256) void k_layer1(
    const float* __restrict__ x, const int* __restrict__ scan,
    const unsigned int* __restrict__ pairs,
    const float* __restrict__ Wrel, const float* __restrict__ Wroot,
    const float* __restrict__ bias,
    float* __restrict__ h_hi, float* __restrict__ h_lo)
{
    __shared__ double sAcc[BNOD * F];
    __shared__ double sR[F * F], sT[F * F], sB[F];
    int t = threadIdx.x, b = blockIdx.x;
    if (t < F * F) { sR[t] = (double)Wrel[t]; sT[t] = (double)Wroot[t]; }
    if (t < F) sB[t] = (double)bias[t];
    for (int i = t; i < BNOD * F; i += 256) sAcc[i] = 0.0;
    __syncthreads();
    long long p0 = scan[b * NPART];
    long long p1 = (b == NBUCK - 1) ? NE : (long long)scan[(b + 1) * NPART];
    for (long long p = p0 + t; p < p1; p += 256) {
        unsigned v = pairs[p];
        const float* xr = x + (long long)(v >> BSH) * F;
        float2 a = *(const float2*)(xr + 0);
        float2 bb = *(const float2*)(xr + 2);
        float2 c = *(const float2*)(xr + 4);
        double* ap = sAcc + (v & (BNOD - 1)) * F;
        unsafeAtomicAdd(ap + 0, (double)a.x);
        unsafeAtomicAdd(ap + 1, (double)a.y);
        unsafeAtomicAdd(ap + 2, (double)bb.x);
        unsafeAtomicAdd(ap + 3, (double)bb.y);
        unsafeAtomicAdd(ap + 4, (double)c.x);
        unsafeAtomicAdd(ap + 5, (double)c.y);
    }
    __syncthreads();
    int nodeBase = b << BSH;
    int numNodes = (NN - nodeBase < BNOD) ? (NN - nodeBase) : BNOD;
    for (int n = t; n < numNodes; n += 256) {
        long long i = nodeBase + n;
        const double* ac = sAcc + n * F;
        const float* xi = x + i * F;
        double xv[F];
        #pragma unroll
        for (int j = 0; j < F; ++j) xv[j] = (double)xi[j];
        float* hh = h_hi + i * F;
        float* hl = h_lo + i * F;
        #pragma unroll
        for (int k = 0; k < F; ++k) {
            double h = sB[k];
            #pragma unroll
            for (int j = 0; j < F; ++j)
                h += ac[j] * sR[k * F + j] + xv[j] * sT[k * F + j];
            float hi = (float)h;
            hh[k] = hi;
            hl[k] = (float)(h - (double)hi);
        }
    }
}

__global__ __launch_bounds__(256) void k_layer2(
    const float* __restrict__ h_hi, const float* __restrict__ h_lo,
    const int* __restrict__ scan, const unsigned int* __restrict__ pairs,
    const float* __restrict__ Wrel, const float* __restrict__ Wroot,
    const float* __restrict__ bias, unsigned char* __restrict__ best)
{
    __shared__ double sAcc[BNOD * F];
    __shared__ double sR[F * F], sT[F * F], sB[F];
    int t = threadIdx.x, b = blockIdx.x;
    if (t < F * F) { sR[t] = (double)Wrel[t]; sT[t] = (double)Wroot[t]; }
    if (t < F) sB[t] = (double)bias[t];
    for (int i = t; i < BNOD * F; i += 256) sAcc[i] = 0.0;
    __syncthreads();
    long long p0 = scan[b * NPART];
    long long p1 = (b == NBUCK - 1) ? NE : (long long)scan[(b + 1) * NPART];
    for (long long p = p0 + t; p < p1; p += 256) {
        unsigned v = pairs[p];
        long long r = (long long)(v >> BSH) * F;
        int dl = (int)(v & (BNOD - 1));
        float2 a  = *(const float2*)(h_hi + r + 0);
        float2 bb = *(const float2*)(h_hi + r + 2);
        float2 c  = *(const float2*)(h_hi + r + 4);
        float2 la = *(const float2*)(h_lo + r + 0);
        float2 lb = *(const float2*)(h_lo + r + 2);
        float2 lc = *(const float2*)(h_lo + r + 4);
        double* ap = sAcc + dl * F;
        unsafeAtomicAdd(ap + 0, (double)a.x + (double)la.x);
        unsafeAtomicAdd(ap + 1, (double)a.y + (double)la.y);
        unsafeAtomicAdd(ap + 2, (double)bb.x + (double)lb.x);
        unsafeAtomicAdd(ap + 3, (double)bb.y + (double)lb.y);
        unsafeAtomicAdd(ap + 4, (double)c.x + (double)lc.x);
        unsafeAtomicAdd(ap + 5, (double)c.y + (double)lc.y);
    }
    __syncthreads();
    int nodeBase = b << BSH;
    int numNodes = (NN - nodeBase < BNOD) ? (NN - nodeBase) : BNOD;
    for (int n = t; n < numNodes; n += 256) {
        long long i = nodeBase + n;
        const double* ac = sAcc + n * F;
        long long ri = i * F;
        double hv[F];
        #pragma unroll
        for (int j = 0; j < F; ++j)
            hv[j] = (double)h_hi[ri + j] + (double)h_lo[ri + j];
        double h2[F];
        #pragma unroll
        for (int k = 0; k < F; ++k) {
            double h = sB[k];
            #pragma unroll
            for (int j = 0; j < F; ++j)
                h += ac[j] * sR[k * F + j] + hv[j] * sT[k * F + j];
            h2[k] = h;
        }
        int bi = 0;
        double bv = h2[0];
        #pragma unroll
        for (int k = 1; k < F; ++k)
            if (h2[k] > bv) { bv = h2[k]; bi = k; }
        best[i] = (unsigned char)bi;
    }
}

__global__ __launch_bounds__(256) void k_onehot(
    const unsigned char* __restrict__ best, float* __restrict__ out)
{
    int i = blockIdx.x * blockDim.x + threadIdx.x;
    if (i >= NN) return;
    int b = best[i];
    float* o = out + (long long)i * F;
    #pragma unroll
    for (int k = 0; k < F; ++k) o[k] = (k == b) ? 1.0f : 0.0f;
}

// ===================== tier C: atomic fallback ==============================
__global__ __launch_bounds__(256) void k_scatter_x(
    const float* __restrict__ x, const int* __restrict__ ei,
    double* __restrict__ agg)
{
    long long e = (long long)blockIdx.x * blockDim.x + threadIdx.x;
    if (e >= NE) return;
    int s = ei[e], d = ei[NE + e];
    const float* xr = x + (long long)s * F;
    double* ar = agg + (long long)d * F;
    float2 a = *(const float2*)(xr + 0);
    float2 b = *(const float2*)(xr + 2);
    float2 c = *(const float2*)(xr + 4);
    unsafeAtomicAdd(ar + 0, (double)a.x);
    unsafeAtomicAdd(ar + 1, (double)a.y);
    unsafeAtomicAdd(ar + 2, (double)b.x);
    unsafeAtomicAdd(ar + 3, (double)b.y);
    unsafeAtomicAdd(ar + 4, (double)c.x);
    unsafeAtomicAdd(ar + 5, (double)c.y);
}

__global__ __launch_bounds__(256) void k_lin1_f(
    const float* __restrict__ x, const double* __restrict__ agg,
    const float* __restrict__ Wrel, const float* __restrict__ Wroot,
    const float* __restrict__ bias, float* __restrict__ h)
{
    __shared__ double sR[F * F], sT[F * F], sB[F];
    int t = threadIdx.x;
    if (t < F * F) { sR[t] = (double)Wrel[t]; sT[t] = (double)Wroot[t]; }
    if (t < F) sB[t] = (double)bias[t];
    __syncthreads();
    long long i = (long long)blockIdx.x * blockDim.x + t;
    if (i >= NN) return;
    const float*  xr = x + i * F;
    const double* ar = agg + i * F;
    double xv[F], av[F];
    #pragma unroll
    for (int j = 0; j < F; ++j) { xv[j] = (double)xr[j]; av[j] = ar[j]; }
    float* hr = h + i * F;
    #pragma unroll
    for (int k = 0; k < F; ++k) {
        double a = sB[k];
        #pragma unroll
        for (int j = 0; j < F; ++j)
            a += av[j] * sR[k * F + j] + xv[j] * sT[k * F + j];
        hr[k] = (float)a;
    }
}

__global__ __launch_bounds__(256) void k_scatter_h32(
    const float* __restrict__ h, const int* __restrict__ ei,
    double* __restrict__ agg)
{
    long long e = (long long)blockIdx.x * blockDim.x + threadIdx.x;
    if (e >= NE) return;
    int s = ei[e], d = ei[NE + e];
    const float* hr = h + (long long)s * F;
    double* ar = agg + (long long)d * F;
    float2 a = *(const float2*)(hr + 0);
    float2 b = *(const float2*)(hr + 2);
    float2 c = *(const float2*)(hr + 4);
    unsafeAtomicAdd(ar + 0, (double)a.x);
    unsafeAtomicAdd(ar + 1, (double)a.y);
    unsafeAtomicAdd(ar + 2, (double)b.x);
    unsafeAtomicAdd(ar + 3, (double)b.y);
    unsafeAtomicAdd(ar + 4, (double)c.x);
    unsafeAtomicAdd(ar + 5, (double)c.y);
}

__global__ __launch_bounds__(256) void k_lin2_f(
    const float* __restrict__ h1, const double* __restrict__ agg,
    const float* __restrict__ Wrel, const float* __restrict__ Wroot,
    const float* __restrict__ bias, float* __restrict__ out)
{
    __shared__ double sR[F * F], sT[F * F], sB[F];
    int t = threadIdx.x;
    if (t < F * F) { sR[t] = (double)Wrel[t]; sT[t] = (double)Wroot[t]; }
    if (t < F) sB[t] = (double)bias[t];
    __syncthreads();
    long long i = (long long)blockIdx.x * blockDim.x + t;
    if (i >= NN) return;
    const float*  hr = h1 + i * F;
    const double* ar = agg + i * F;
    double hv[F], av[F];
    #pragma unroll
    for (int j = 0; j < F; ++j) { hv[j] = (double)hr[j]; av[j] = ar[j]; }
    double h2[F];
    #pragma unroll
    for (int k = 0; k < F; ++k) {
        double a = sB[k];
        #pragma unroll
        for (int j = 0; j < F; ++j)
            a += av[j] * sR[k * F + j] + hv[j] * sT[k * F + j];
        h2[k] = a;
    }
    int b = 0;
    double bv = h2[0];
    #pragma unroll
    for (int k = 1; k < F; ++k)
        if (h2[k] > bv) { bv = h2[k]; b = k; }
    float* o = out + i * F;
    #pragma unroll
    for (int k = 0; k < F; ++k) o[k] = (k == b) ? 1.0f : 0.0f;
}

// ============================================================================
extern "C" void kernel_launch(void* const* d_in, const int* in_sizes, int n_in,
                              void* d_out, int out_size, void* d_ws, size_t ws_size,
                              hipStream_t stream) {
    const float* x      = (const float*)d_in[0];
    const int*   ei     = (const int*)d_in[1];
    const float* Wrel1  = (const float*)d_in[2];
    const float* Wroot1 = (const float*)d_in[3];
    const float* b1     = (const float*)d_in[4];
    const float* Wrel2  = (const float*)d_in[5];
    const float* Wroot2 = (const float*)d_in[6];
    const float* b2     = (const float*)d_in[7];
    float* out = (float*)d_out;

    const int nb = (NN + 255) / 256;
    const int scanBlocks = (SCANN + SCAN_B - 1) / SCAN_B;   // 1909
    const int cpBlocks = (int)((NE / 4 + 255) / 256);

    // ---- tier A layouts ---------------------------------------------------
    size_t o_pairs = 0;                                    // 64 MB
    size_t o_scan  = o_pairs + (size_t)NE * 4;             // ~1.9 MB
    size_t o_bsum  = o_scan + (size_t)SCANN * 4;
    size_t o_xp    = (o_bsum + 16384 + 63) & ~(size_t)63;  // 32 MB, 64B-aligned
    size_t o_h1p   = o_xp + (size_t)NN * 8 * 4;            // 64 MB, 64B-aligned
    size_t needA   = o_h1p + (size_t)NN * 8 * 8;           // ~162 MB
    size_t o_srt2  = needA;                                // 64 MB (A++ only)
    size_t needApp = o_srt2 + (size_t)NE * 4;              // ~226 MB

    // ---- tier B layout ----------------------------------------------------
    size_t b_hlo   = (o_bsum + 16384 + 15) & ~(size_t)15;
    size_t b_best  = b_hlo + (size_t)NN * F * 4;
    size_t needB   = b_best + (size_t)NN;                  // ~91 MB

    if (ws_size >= needA) {
        char* ws = (char*)d_ws;
        unsigned int* pairs = (unsigned int*)(ws + o_pairs);
        int*    scan = (int*)(ws + o_scan);
        int*    bsum = (int*)(ws + o_bsum);
        float*  xp   = (float*)(ws + o_xp);
        double* h1p  = (double*)(ws + o_h1p);
        bool big = (ws_size >= needApp);
        unsigned int* sorted = big ? (unsigned int*)(ws + o_srt2)
                                   : (unsigned int*)(ws + o_h1p);
        const unsigned int* lpairs = big ? sorted : pairs;

        k_bhist<<<NPART, 256, 0, stream>>>(ei, scan);
        k_xpad<<<nb, 256, 0, stream>>>(x, xp);
        k_scan_bsum<<<scanBlocks, SCAN_B, 0, stream>>>(scan, bsum, SCANN);
        k_scan_top<<<1, SCAN_B, 0, stream>>>(bsum, scanBlocks);
        k_scan_final<<<scanBlocks, SCAN_B, 0, stream>>>(scan, bsum, SCANN);
        k_partition<<<NPART, 256, 0, stream>>>(ei, scan, pairs);
        k_srcsort<<<NBUCK, 256, 0, stream>>>(scan, pairs, sorted);
        if (!big)
            k_copypairs<<<cpBlocks, 256, 0, stream>>>((const uint4*)sorted, (uint4*)pairs);
        k_layer1p<<<NBUCK, 256, 0, stream>>>(xp, scan, lpairs, Wrel1, Wroot1, b1, h1p);
        k_layer2p<<<NBUCK, 256, 0, stream>>>(h1p, scan, lpairs, Wrel2, Wroot2, b2, out);
    } else if (ws_size >= needB) {
        char* ws = (char*)d_ws;
        unsigned int* pairs = (unsigned int*)(ws + o_pairs);
        int*   scan  = (int*)(ws + o_scan);
        int*   bsum  = (int*)(ws + o_bsum);
        float* h_lo  = (float*)(ws + b_hlo);
        unsigned char* best = (unsigned char*)(ws + b_best);
        float* h_hi = out;

        k_bhist<<<NPART, 256, 0, stream>>>(ei, scan);
        k_scan_bsum<<<scanBlocks, SCAN_B, 0, stream>>>(scan, bsum, SCANN);
        k_scan_top<<<1, SCAN_B, 0, stream>>>(bsum, scanBlocks);
        k_scan_final<<<scanBlocks, SCAN_B, 0, stream>>>(scan, bsum, SCANN);
        k_partition<<<NPART, 256, 0, stream>>>(ei, scan, pairs);
        k_layer1<<<NBUCK, 256, 0, stream>>>(x, scan, pairs, Wrel1, Wroot1, b1, h_hi, h_lo);
        k_layer2<<<NBUCK, 256, 0, stream>>>(h_hi, h_lo, scan, pairs, Wrel2, Wroot2, b2, best);
        k_onehot<<<nb, 256, 0, stream>>>(best, out);
    } else {
        double* agg = (double*)d_ws;
        const size_t aggBytes = (size_t)NN * F * sizeof(double);
        const int eb = (int)((NE + 255) / 256);
        float* h1f = out;
        hipMemsetAsync(agg, 0, aggBytes, stream);
        k_scatter_x<<<eb, 256, 0, stream>>>(x, ei, agg);
        k_lin1_f<<<nb, 256, 0, stream>>>(x, agg, Wrel1, Wroot1, b1, h1f);
        hipMemsetAsync(agg, 0, aggBytes, stream);
        k_scatter_h32<<<eb, 256, 0, stream>>>(h1f, ei, agg);
        k_lin2_f<<<nb, 256, 0, stream>>>(h1f, agg, Wrel2, Wroot2, b2, out);
    }
}